// Round 13
// baseline (2937.584 us; speedup 1.0000x reference)
//
#include <hip/hip_runtime.h>
#include <hip/hip_bf16.h>
#include <cstdint>
#include <cstddef>

#define B_   2
#define S_   1024
#define V_   8192
#define D_   1024
#define H_   16
#define KVH_ 4
#define L_   8
#define HD_  64
#define KV_  256
#define HID_ 2736
#define HIDP 2752
#define NT_  (B_*S_)
#define EPSF 1.1920928955078125e-7f
#define SOFTCAPF 30.0f

typedef __bf16 bf8 __attribute__((ext_vector_type(8)));
typedef __bf16 bf4 __attribute__((ext_vector_type(4)));
typedef float  f4  __attribute__((ext_vector_type(4)));

// ---------------- wave / block reductions ----------------
__device__ __forceinline__ float wsum(float v){
#pragma unroll
  for (int m = 32; m >= 1; m >>= 1) v += __shfl_xor(v, m, 64);
  return v;
}
__device__ __forceinline__ float blocksum256(float v){
  __shared__ float red[4];
  v = wsum(v);
  if ((threadIdx.x & 63) == 0) red[threadIdx.x >> 6] = v;
  __syncthreads();
  return red[0] + red[1] + red[2] + red[3];
}
__device__ __forceinline__ float4 ld4b(const __bf16* p, size_t i4){
  bf4 v = ((const bf4*)p)[i4];
  return make_float4((float)v[0], (float)v[1], (float)v[2], (float)v[3]);
}

// ---------------- register-direct GEMM: no LDS staging, no K-loop barriers ----------------
// Block = 4 independent waves (2x2), each computes a 64x64 tile of the 128x128
// block tile. Fragments loaded straight from global (L2-resident panels),
// 2-deep register double-buffer -> compiler interleaves loads with MFMAs and
// emits counted waitcnts (no barrier to defeat scheduling). XCD-swizzled grid.
// OUT: 1 = bf16 store; 2 = LM epilogue (bigram gather + softcap, LDS staged).
template<int OUT>
__global__ __launch_bounds__(256) void k_gemmr(
    const __bf16* __restrict__ A, const __bf16* __restrict__ Wt,
    void* __restrict__ Cv, int M, int N, int K, int lda, int mtiles,
    const int* __restrict__ idx, const float* __restrict__ gateb,
    const float* __restrict__ bhd, const float* __restrict__ bsc,
    const float* __restrict__ ub)
{
  __shared__ __attribute__((aligned(16))) float EP[(OUT == 2) ? 64*128 : 4];

  const int tid = threadIdx.x;
  const int nwg = gridDim.x;
  const int wg  = (blockIdx.x & 7) * (nwg >> 3) + (blockIdx.x >> 3);
  const int bm  = wg % mtiles, bn = wg / mtiles;
  const int m0  = bm << 7, n0 = bn << 7;
  const int l = tid & 63, wv = tid >> 6;
  const int wr = (wv >> 1) << 6;     // wave row quadrant (0/64)
  const int wc = (wv & 1) << 6;      // wave col quadrant (0/64)
  const int fr = l & 15, g = l >> 4;

  f4 acc[4][4] = {};

  const __bf16* ap[4];
  const __bf16* bp[4];
#pragma unroll
  for (int i = 0; i < 4; ++i)
    ap[i] = A + (size_t)(m0 + wr + i*16 + fr) * lda + g*8;
#pragma unroll
  for (int j = 0; j < 4; ++j) {
    int rB = n0 + wc + j*16 + fr; if (rB > N-1) rB = N-1;
    bp[j] = Wt + (size_t)rB * K + g*8;
  }

#define MFMA16(AF, BF) do { \
    _Pragma("unroll") \
    for (int i = 0; i < 4; ++i) \
      _Pragma("unroll") \
      for (int j = 0; j < 4; ++j) \
        acc[i][j] = __builtin_amdgcn_mfma_f32_16x16x32_bf16(AF[i], BF[j], acc[i][j], 0, 0, 0); \
  } while (0)

  bf8 a0[4], b0[4], a1[4], b1[4];
#pragma unroll
  for (int i = 0; i < 4; ++i) { a0[i] = *(const bf8*)(ap[i]); b0[i] = *(const bf8*)(bp[i]); }

  for (int k0 = 0; k0 + 64 <= K; k0 += 64) {
#pragma unroll
    for (int i = 0; i < 4; ++i) {
      a1[i] = *(const bf8*)(ap[i] + k0 + 32);
      b1[i] = *(const bf8*)(bp[i] + k0 + 32);
    }
    MFMA16(a0, b0);
    if (k0 + 64 < K) {
#pragma unroll
      for (int i = 0; i < 4; ++i) {
        a0[i] = *(const bf8*)(ap[i] + k0 + 64);
        b0[i] = *(const bf8*)(bp[i] + k0 + 64);
      }
    }
    MFMA16(a1, b1);
  }
#undef MFMA16

  if constexpr (OUT == 2) {
    // LM epilogue: 2 passes of 64 rows staged in LDS [64][128] f32.
#pragma unroll
    for (int pass = 0; pass < 2; ++pass) {
      __syncthreads();
      if ((wv >> 1) == pass) {
#pragma unroll
        for (int i = 0; i < 4; ++i)
#pragma unroll
          for (int j = 0; j < 4; ++j)
#pragma unroll
            for (int r = 0; r < 4; ++r)
              EP[(i*16 + g*4 + r)*128 + wc + j*16 + fr] = acc[i][j][r];
      }
      __syncthreads();
#pragma unroll
      for (int it = 0; it < 8; ++it) {
        int row = it*8 + (tid >> 5);
        int c0  = (tid & 31) << 2;
        int grow = m0 + pass*64 + row;
        int gn   = n0 + c0;
        float gt = gateb[grow];
        int   tk = idx[grow];
        float4 a4 = *(float4*)&EP[row*128 + c0];
        float4 b4 = *(const float4*)&bhd[(size_t)tk * V_ + gn];
        float4 u4 = *(const float4*)&ub[gn];
        float4 s4 = *(const float4*)&bsc[gn];
        float4 o;
        o.x = SOFTCAPF * tanhf((a4.x + u4.x + gt*b4.x*s4.x) / SOFTCAPF);
        o.y = SOFTCAPF * tanhf((a4.y + u4.y + gt*b4.y*s4.y) / SOFTCAPF);
        o.z = SOFTCAPF * tanhf((a4.z + u4.z + gt*b4.z*s4.z) / SOFTCAPF);
        o.w = SOFTCAPF * tanhf((a4.w + u4.w + gt*b4.w*s4.w) / SOFTCAPF);
        *(float4*)&((float*)Cv)[(size_t)grow * N + gn] = o;
      }
    }
  } else {
    const int rbase = g << 2;
#pragma unroll
    for (int i = 0; i < 4; ++i) {
      int gm = m0 + wr + i*16 + rbase;
#pragma unroll
      for (int j = 0; j < 4; ++j) {
        int gn = n0 + wc + j*16 + fr;
        if (gn < N) {
#pragma unroll
          for (int r = 0; r < 4; ++r)
            ((__bf16*)Cv)[(size_t)(gm + r) * N + gn] = (__bf16)acc[i][j][r];
        }
      }
    }
  }
}

// ---------------- weight f32 -> bf16 convert ----------------
__global__ void k_cvt(const float* __restrict__ s, __bf16* __restrict__ d,
                      int perL, int K, int Kpad, long dstL, long dstOff, long nd4)
{
  long i = (long)blockIdx.x * 256 + threadIdx.x;
  if (i >= nd4) return;
  const int kp4 = Kpad >> 2;
  long row = i / kp4;
  int  c   = (int)(i % kp4) << 2;
  long layer = row / perL, r = row % perL;
  bf4 o;
  if (c < K) {
    float4 v = *(const float4*)(s + (layer*perL + r) * (long)K + c);
    o[0] = (__bf16)v.x; o[1] = (__bf16)v.y; o[2] = (__bf16)v.z; o[3] = (__bf16)v.w;
  } else { o[0] = o[1] = o[2] = o[3] = (__bf16)0.f; }
  *(bf4*)(d + layer*dstL + dstOff + (long)r*Kpad + c) = o;
}

// ---------------- embedding + rmsnorm ----------------
__global__ void k_embed(const int* __restrict__ idx, const float* __restrict__ emb,
                        const float* __restrict__ wn, float* __restrict__ x, float* __restrict__ x0)
{
  const int r = blockIdx.x, t = threadIdx.x;
  const float4 v = ((const float4*)(emb + (size_t)idx[r] * D_))[t];
  float ss = blocksum256(v.x*v.x + v.y*v.y + v.z*v.z + v.w*v.w);
  float rs = rsqrtf(ss / (float)D_ + EPSF);
  const float4 w = ((const float4*)wn)[t];
  float4 o = make_float4(v.x*rs*w.x, v.y*rs*w.y, v.z*rs*w.z, v.w*rs*w.w);
  ((float4*)(x  + (size_t)r * D_))[t] = o;
  ((float4*)(x0 + (size_t)r * D_))[t] = o;
}

// ---------------- block start: [x += msc*t1] [skip store] [skip add] mix + norm ----------------
__global__ void k_blockstart(
    float* __restrict__ x, const float* __restrict__ x0,
    const __bf16* __restrict__ t1, const float* __restrict__ msc,
    float* __restrict__ skstore, const float* __restrict__ skread, int same,
    const float* __restrict__ skw, const float* __restrict__ skg,
    const float* __restrict__ mix, const float* __restrict__ nw,
    __bf16* __restrict__ xn)
{
  const int r = blockIdx.x, t = threadIdx.x;
  const size_t i4 = (size_t)r * 256 + t;
  float4 xv = ((float4*)x)[i4];
  if (t1) {
    float4 tv = ld4b(t1, i4);
    float4 s  = ((const float4*)msc)[t];
    xv.x += s.x*tv.x; xv.y += s.y*tv.y; xv.z += s.z*tv.z; xv.w += s.w*tv.w;
  }
  if (skstore) ((float4*)skstore)[i4] = xv;
  if (skw) {
    float4 sv;
    if (same) sv = xv;
    else      sv = ((const float4*)skread)[i4];
    float4 w = ((const float4*)skw)[t];
    float4 g = ((const float4*)skg)[t];
    xv.x += w.x / (1.f + __expf(-g.x)) * sv.x;
    xv.y += w.y / (1.f + __expf(-g.y)) * sv.y;
    xv.z += w.z / (1.f + __expf(-g.z)) * sv.z;
    xv.w += w.w / (1.f + __expf(-g.w)) * sv.w;
  }
  float4 x0v = ((const float4*)x0)[i4];
  float4 m0  = ((const float4*)mix)[t];
  float4 m1  = ((const float4*)(mix + D_))[t];
  float4 nv;
  nv.x = m0.x*xv.x + m1.x*x0v.x; nv.y = m0.y*xv.y + m1.y*x0v.y;
  nv.z = m0.z*xv.z + m1.z*x0v.z; nv.w = m0.w*xv.w + m1.w*x0v.w;
  ((float4*)x)[i4] = nv;
  float ss = blocksum256(nv.x*nv.x + nv.y*nv.y + nv.z*nv.z + nv.w*nv.w);
  float rs = rsqrtf(ss / (float)D_ + EPSF);
  const float4 w = ((const float4*)nw)[t];
  bf4 o = { (__bf16)(nv.x*rs*w.x), (__bf16)(nv.y*rs*w.y),
            (__bf16)(nv.z*rs*w.z), (__bf16)(nv.w*rs*w.w) };
  ((bf4*)xn)[i4] = o;
}

// ---------------- x += sc*t1 ; xn = bf16(rmsnorm(x)*nw) ; optional bigram gate ----------------
__global__ void k_addnorm(float* __restrict__ x, const __bf16* __restrict__ t1,
                          const float* __restrict__ sc, const float* __restrict__ nw,
                          __bf16* __restrict__ xn,
                          const float* __restrict__ bg, float* __restrict__ gateb)
{
  const int r = blockIdx.x, t = threadIdx.x;
  const size_t i4 = (size_t)r * 256 + t;
  float4 xv = ((float4*)x)[i4];
  float4 tv = ld4b(t1, i4);
  float4 s  = ((const float4*)sc)[t];
  xv.x += s.x*tv.x; xv.y += s.y*tv.y; xv.z += s.z*tv.z; xv.w += s.w*tv.w;
  ((float4*)x)[i4] = xv;
  float ss = blocksum256(xv.x*xv.x + xv.y*xv.y + xv.z*xv.z + xv.w*xv.w);
  float rs = rsqrtf(ss / (float)D_ + EPSF);
  const float4 w = ((const float4*)nw)[t];
  float ox = xv.x*rs*w.x, oy = xv.y*rs*w.y, oz = xv.z*rs*w.z, ow = xv.w*rs*w.w;
  bf4 o = { (__bf16)ox, (__bf16)oy, (__bf16)oz, (__bf16)ow };
  ((bf4*)xn)[i4] = o;
  if (bg) {
    float4 b4 = ((const float4*)bg)[t];
    float gd = ox*b4.x + oy*b4.y + oz*b4.z + ow*b4.w;
    __syncthreads();
    float gs = blocksum256(gd);
    if (t == 0) gateb[r] = 1.f / (1.f + __expf(-gs));
  }
}

// ---------------- rmsnorm D=1024, f32 in -> bf16 out ----------------
__global__ void k_rmsnormb(const float* __restrict__ in, const float* __restrict__ w,
                           __bf16* __restrict__ out)
{
  const int r = blockIdx.x, t = threadIdx.x;
  float4 v = ((const float4*)(in + (size_t)r * D_))[t];
  float ss = blocksum256(v.x*v.x + v.y*v.y + v.z*v.z + v.w*v.w);
  float rs = rsqrtf(ss / (float)D_ + EPSF);
  const float4 w4 = ((const float4*)w)[t];
  bf4 o = { (__bf16)(v.x*rs*w4.x), (__bf16)(v.y*rs*w4.y),
            (__bf16)(v.z*rs*w4.z), (__bf16)(v.w*rs*w4.w) };
  ((bf4*)(out + (size_t)r * D_))[t] = o;
}

// ---------------- dwconv helper (bf16 strided buffer) ----------------
__device__ __forceinline__ float conv3b(const __bf16* buf, int tok, int s, int ld, int col,
                                        const float* w, int C, int c){
  const __bf16* p0 = buf + (size_t)tok * ld + col;
  float a  = (s >= 2) ? (float)p0[-2*ld] : 0.f;
  float bb = (s >= 1) ? (float)p0[-ld]   : 0.f;
  return w[c]*a + w[C + c]*bb + w[2*C + c]*(float)p0[0];
}

// ---------------- QKV prep: dwconv + head-rmsnorm + RoPE + q_gain -> bf16 (256 thr) ----------------
__global__ __launch_bounds__(256) void k_prep(
    const __bf16* __restrict__ qkv,
    const float* __restrict__ qcw, const float* __restrict__ kcw, const float* __restrict__ vcw,
    const float* __restrict__ qgain,
    __bf16* __restrict__ q2, __bf16* __restrict__ k2, __bf16* __restrict__ v2)
{
  const int tok = blockIdx.x;
  const int s = tok & (S_ - 1);
  const int t = threadIdx.x, lane = t & 63, w = t >> 6;
  __shared__ float qsh[1024];

  const int j = lane & 31;
  float freq = __expf(-(float)j * (9.210340371976184f / 32.f));
  float sn, cs;
  __sincosf((float)s * freq, &sn, &cs);

#pragma unroll
  for (int k = 0; k < 4; ++k) {
    int c = t + k*256;
    float qc = conv3b(qkv, tok, s, 1536, c, qcw, D_, c);
    float ssq = wsum(qc * qc);
    float qn = qc * rsqrtf(ssq / 64.f + EPSF);
    float pr = __shfl_xor(qn, 32, 64);
    qsh[c] = qn * cs + ((lane < 32) ? pr * sn : -pr * sn);
  }
  __syncthreads();
  float qg[16];
#pragma unroll
  for (int g = 0; g < 16; ++g) qg[g] = qsh[g*64 + lane];
#pragma unroll
  for (int k = 0; k < 4; ++k) {
    int h = (k << 2) + w;
    float acc = 0.f;
#pragma unroll
    for (int g = 0; g < 16; ++g) acc += qgain[h*16 + g] * qg[g];
    q2[(size_t)tok * D_ + h*64 + lane] = (__bf16)acc;
  }

  {
    float kc = conv3b(qkv, tok, s, 1536, 1024 + t, kcw, KV_, t);
    float ssk = wsum(kc * kc);
    float kn = kc * rsqrtf(ssk / 64.f + EPSF);
    float pk = __shfl_xor(kn, 32, 64);
    k2[(size_t)tok * KV_ + t] = (__bf16)(kn * cs + ((lane < 32) ? pk * sn : -pk * sn));
  }
  v2[(size_t)tok * KV_ + t] = (__bf16)conv3b(qkv, tok, s, 1536, 1280 + t, vcw, KV_, t);
}

// ---------------- MFMA flash attention: KVBLK=128 (bf16 compute, f32 accumulate) ----------------
#define LDK 72     // K row stride (64 hd + 8)
#define LDP 136    // Vt / Ps row stride (128 keys + 8)
__global__ __launch_bounds__(256) void k_attn(
    const __bf16* __restrict__ q2, const __bf16* __restrict__ k2,
    const __bf16* __restrict__ v2, float* __restrict__ y)
{
  __shared__ __attribute__((aligned(16))) __bf16 Ks[128*LDK];
  __shared__ __attribute__((aligned(16))) __bf16 Vt[64*LDP];
  __shared__ __attribute__((aligned(16))) __bf16 Ps[4][16*LDP];

  const int id = blockIdx.x;
  const int qb = id & 15;
  const int h  = (id >> 4) & 15;
  const int b  = id >> 8;
  const int tid = threadIdx.x, l = tid & 63, wq = tid >> 6;
  const int g = l >> 4, fr = l & 15;
  const int kvh = h >> 2;
  const int qrow = qb*64 + wq*16 + fr;

  bf8 qf[2];
#pragma unroll
  for (int ks = 0; ks < 2; ++ks)
    qf[ks] = *(const bf8*)&q2[(size_t)(b*S_ + qrow)*D_ + h*64 + g*8 + ks*32];

  float m = -1e30f, lsum = 0.f;
  f4 acc[4] = {};

  const int nch = (qb >> 1) + 1;
  for (int ch = 0; ch < nch; ++ch) {
    const int t0 = ch << 7;
    __syncthreads();
#pragma unroll
    for (int it = 0; it < 4; ++it) {
      int i = tid + it*256;
      int row = i >> 3, seg = (i & 7) << 3;
      *(bf8*)&Ks[row*LDK + seg] =
        *(const bf8*)&k2[(size_t)(b*S_ + t0 + row)*KV_ + kvh*64 + seg];
    }
    {
      int key4 = (tid & 31) << 2, hd8 = (tid >> 5) << 3;
      bf8 vv[4];
#pragma unroll
      for (int kk = 0; kk < 4; ++kk)
        vv[kk] = *(const bf8*)&v2[(size_t)(b*S_ + t0 + key4 + kk)*KV_ + kvh*64 + hd8];
#pragma unroll
      for (int hh = 0; hh < 8; ++hh) {
        bf4 w = { vv[0][hh], vv[1][hh], vv[2][hh], vv[3][hh] };
        *(bf4*)&Vt[(hd8 + hh)*LDP + key4] = w;
      }
    }
    __syncthreads();

    f4 sc[8] = {};
#pragma unroll
    for (int ks = 0; ks < 2; ++ks)
#pragma unroll
      for (int t = 0; t < 8; ++t) {
        bf8 kf = *(const bf8*)&Ks[(t*16 + fr)*LDK + g*8 + ks*32];
        sc[t] = __builtin_amdgcn_mfma_f32_16x16x32_bf16(kf, qf[ks], sc[t], 0, 0, 0);
      }

    const bool lastch = (ch == nch - 1);
    float s[8][4];
    float pmax = -1e30f;
#pragma unroll
    for (int t = 0; t < 8; ++t)
#pragma unroll
      for (int r = 0; r < 4; ++r) {
        float v = sc[t][r] * 0.125f;
        if (lastch && (t0 + t*16 + g*4 + r > qrow)) v = -1e30f;
        s[t][r] = v;
        pmax = fmaxf(pmax, v);
      }
    pmax = fmaxf(pmax, __shfl_xor(pmax, 16, 64));
    pmax = fmaxf(pmax, __shfl_xor(pmax, 32, 64));
    float mnew = fmaxf(m, pmax);
    float alpha = __expf(m - mnew);
    float rs = 0.f;
#pragma unroll
    for (int t = 0; t < 8; ++t)
#pragma unroll
      for (int r = 0; r < 4; ++r) { float p = __expf(s[t][r] - mnew); s[t][r] = p; rs += p; }
    rs += __shfl_xor(rs, 16, 64);
    rs += __shfl_xor(rs, 32, 64);
    lsum = lsum * alpha + rs;
    m = mnew;
#pragma unroll
    for (int t = 0; t < 4; ++t) acc[t] = acc[t] * alpha;

#pragma unroll
    for (int t = 0; t < 8; ++t) {
      bf4 pw = { (__bf16)s[t][0], (__bf16)s[t][1], (__bf16)s[t][2], (__bf16)s[t][3] };
      *(bf4*)&Ps[wq][fr*LDP + t*16 + g*4] = pw;
    }

#pragma unroll
    for (int ks = 0; ks < 4; ++ks) {
      bf8 pf = *(const bf8*)&Ps[wq][fr*LDP + g*8 + ks*32];
#pragma unroll
      for (int t = 0; t < 4; ++t) {
        bf8 vf = *(const bf8*)&Vt[(t*16 + fr)*LDP + g*8 + ks*32];
        acc[t] = __builtin_amdgcn_mfma_f32_16x16x32_bf16(vf, pf, acc[t], 0, 0, 0);
      }
    }
  }

  float inv = 1.f / lsum;
#pragma unroll
  for (int t = 0; t < 4; ++t)
#pragma unroll
    for (int r = 0; r < 4; ++r)
      y[(size_t)(b*S_ + qrow)*D_ + h*64 + t*16 + g*4 + r] = acc[t][r] * inv;
}

// ---------------- fused silu*mul + dwconv + rmsnorm -> bf16 (reads bf16 hb) ----------------
__device__ __forceinline__ float hprodb(const __bf16* row, int c){
  float a = (float)row[c], b = (float)row[HID_ + c];
  return a * b / (1.f + __expf(-b));
}
__global__ __launch_bounds__(256) void k_hfuse(
    const __bf16* __restrict__ hb, const float* __restrict__ cw,
    const float* __restrict__ nw, __bf16* __restrict__ out)
{
  const int tok = blockIdx.x, t = threadIdx.x;
  const int s = tok & (S_ - 1);
  const __bf16* row0 = hb + (size_t)tok * 5472;
  float v[11]; float ss = 0.f;
#pragma unroll
  for (int ii = 0; ii < 11; ++ii) {
    int c = t + ii*256;
    float cv = 0.f;
    if (c < HID_) {
      float p0 = hprodb(row0, c);
      float p1 = (s >= 1) ? hprodb(row0 - 5472, c) : 0.f;
      float p2 = (s >= 2) ? hprodb(row0 - 2*5472, c) : 0.f;
      cv = cw[c]*p2 + cw[HID_ + c]*p1 + cw[2*HID_ + c]*p0;
    }
    v[ii] = cv; ss += cv*cv;
  }
  ss = blocksum256(ss);
  float rs = rsqrtf(ss / (float)HID_ + EPSF);
#pragma unroll
  for (int ii = 0; ii < 11; ++ii) {
    int c = t + ii*256;
    if (c < HIDP)
      out[(size_t)tok * HIDP + c] = (c < HID_) ? (__bf16)(v[ii]*rs*nw[c]) : (__bf16)0.f;
  }
}

// ---------------- host ----------------
template<int OUT>
static inline void gemmr(const __bf16* A, const __bf16* W, void* C, int M, int N, int K,
                         int lda, hipStream_t s,
                         const int* idx = nullptr, const float* gateb = nullptr,
                         const float* bhd = nullptr, const float* bsc = nullptr,
                         const float* ub = nullptr)
{
  int mt = M >> 7, nt = (N + 127) >> 7;
  k_gemmr<OUT><<<dim3(mt * nt), dim3(256), 0, s>>>(A, W, C, M, N, K, lda, mt,
                                                   idx, gateb, bhd, bsc, ub);
}

extern "C" void kernel_launch(void* const* d_in, const int* in_sizes, int n_in,
                              void* d_out, int out_size, void* d_ws, size_t ws_size,
                              hipStream_t stream)
{
  const int*   idx    = (const int*)d_in[0];
  const float* temb   = (const float*)d_in[1];
  const float* enw    = (const float*)d_in[2];
  const float* rmix   = (const float*)d_in[3];
  const float* anw    = (const float*)d_in[4];
  const float* mnw    = (const float*)d_in[5];
  const float* ascale = (const float*)d_in[6];
  const float* mscale = (const float*)d_in[7];
  const float* Wq     = (const float*)d_in[8];
  const float* Wk     = (const float*)d_in[9];
  const float* Wv     = (const float*)d_in[10];
  const float* qcw    = (const float*)d_in[11];
  const float* kcw    = (const float*)d_in[12];
  const float* vcw    = (const float*)d_in[13];
  const float* qgain  = (const float*)d_in[14];
  const float* panw   = (const float*)d_in[15];
  const float* Wo     = (const float*)d_in[16];
  const float* Wfc    = (const float*)d_in[17];
  const float* Wgate  = (const float*)d_in[18];
  const float* hcw    = (const float*)d_in[19];
  const float* hnw    = (const float*)d_in[20];
  const float* Wmp    = (const float*)d_in[21];
  const float* skw    = (const float*)d_in[22];
  const float* skg    = (const float*)d_in[23];
  const float* fnw    = (const float*)d_in[24];
  const float* lmw    = (const float*)d_in[25];
  const float* bh     = (const float*)d_in[26];
  const float* bsc    = (const float*)d_in[27];
  const float* bg     = (const float*)d_in[28];
  const float* ub     = (const float*)d_in[29];

  float* p = (float*)d_ws;
  float* x    = p; p += (size_t)NT_ * D_;
  float* x0   = p; p += (size_t)NT_ * D_;
  float* y    = p; p += (size_t)NT_ * D_;
  float* skips= p; p += (size_t)4 * NT_ * D_;
  float* gateb= p; p += NT_;
  __bf16* qkvb= (__bf16*)p; p += (size_t)NT_ * 1536 / 2;
  __bf16* hbb = (__bf16*)p; p += (size_t)NT_ * 5472 / 2;
  __bf16* t1b = (__bf16*)p; p += (size_t)NT_ * D_ / 2;
  __bf16* xnb = (__bf16*)p; p += (size_t)NT_ * D_ / 2;
  __bf16* q2b = (__bf16*)p; p += (size_t)NT_ * D_ / 2;
  __bf16* k2b = (__bf16*)p; p += (size_t)NT_ * KV_ / 2;
  __bf16* v2b = (__bf16*)p; p += (size_t)NT_ * KV_ / 2;
  __bf16* hnb = (__bf16*)p; p += (size_t)NT_ * HIDP / 2;
  __bf16* wqkv= (__bf16*)p; p += (size_t)L_ * 1536 * 1024 / 2;
  __bf16* wob = (__bf16*)p; p += (size_t)L_ * 1024 * 1024 / 2;
  __bf16* wfcg= (__bf16*)p; p += (size_t)L_ * 5472 * 1024 / 2;
  __bf16* wmpb= (__bf16*)p; p += (size_t)L_ * 1024 * HIDP / 2;
  __bf16* wlmb= (__bf16*)p; p += (size_t)V_ * 1024 / 2;
  float* logits = (float*)d_out;

  // ---- weight conversions (every launch; deterministic) ----
  auto cvt = [&](const float* s, __bf16* d, int perL, int K, int Kpad,
                 long dstL, long dstOff, int nl) {
    long nd4 = (long)nl * perL * (Kpad >> 2);
    int grid = (int)((nd4 + 255) / 256);
    k_cvt<<<grid, 256, 0, stream>>>(s, d, perL, K, Kpad, dstL, dstOff, nd4);
  };
  cvt(Wq,    wqkv, 1024, 1024, 1024, 1536L*1024, 0,          L_);
  cvt(Wk,    wqkv,  256, 1024, 1024, 1536L*1024, 1024L*1024, L_);
  cvt(Wv,    wqkv,  256, 1024, 1024, 1536L*1024, 1280L*1024, L_);
  cvt(Wo,    wob,  1024, 1024, 1024, 1024L*1024, 0,          L_);
  cvt(Wfc,   wfcg, 2736, 1024, 1024, 5472L*1024, 0,          L_);
  cvt(Wgate, wfcg, 2736, 1024, 1024, 5472L*1024, 2736L*1024, L_);
  cvt(Wmp,   wmpb, 1024, 2736, HIDP, 1024L*HIDP, 0,          L_);
  cvt(lmw,   wlmb, 8192, 1024, 1024, 8192L*1024, 0,          1);

  k_embed<<<NT_, 256, 0, stream>>>(idx, temb, enw, x, x0);

  for (int i = 0; i < L_; ++i) {
    const float* pmsc = (i > 0) ? mscale + (size_t)(i-1) * D_ : nullptr;
    float* skst = (i >= 1 && i <= 4) ? skips + (size_t)(i-1) * NT_ * D_ : nullptr;
    const float* skrd = (i >= 4) ? skips + (size_t)(7-i) * NT_ * D_ : nullptr;
    const float* swp = (i >= 4) ? skw + (size_t)(i-4) * D_ : nullptr;
    const float* sgp = (i >= 4) ? skg + (size_t)(i-4) * D_ : nullptr;
    k_blockstart<<<NT_, 256, 0, stream>>>(x, x0, (i > 0) ? t1b : nullptr, pmsc,
                                          skst, skrd, (i == 4) ? 1 : 0, swp, sgp,
                                          rmix + (size_t)i * 2 * D_,
                                          anw + (size_t)i * D_, xnb);
    gemmr<1>(xnb, wqkv + (size_t)i * 1536 * 1024, qkvb, NT_, 1536, 1024, 1024, stream);
    k_prep<<<NT_, 256, 0, stream>>>(qkvb,
                                    qcw + (size_t)i * 3 * D_, kcw + (size_t)i * 3 * KV_,
                                    vcw + (size_t)i * 3 * KV_, qgain + (size_t)i * H_ * H_,
                                    q2b, k2b, v2b);
    k_attn<<<B_ * H_ * (S_/64), 256, 0, stream>>>(q2b, k2b, v2b, y);
    k_rmsnormb<<<NT_, 256, 0, stream>>>(y, panw + (size_t)i * D_, xnb);
    gemmr<1>(xnb, wob + (size_t)i * 1024 * 1024, t1b, NT_, 1024, 1024, 1024, stream);
    k_addnorm<<<NT_, 256, 0, stream>>>(x, t1b, ascale + (size_t)i * D_,
                                       mnw + (size_t)i * D_, xnb, nullptr, nullptr);
    gemmr<1>(xnb, wfcg + (size_t)i * 5472 * 1024, hbb, NT_, 5472, 1024, 1024, stream);
    k_hfuse<<<NT_, 256, 0, stream>>>(hbb, hcw + (size_t)i * 3 * HID_,
                                     hnw + (size_t)i * HID_, hnb);
    gemmr<1>(hnb, wmpb + (size_t)i * 1024 * HIDP, t1b, NT_, 1024, HIDP, HIDP, stream);
  }

  // final: mlp7 residual + final norm + bigram gate
  k_addnorm<<<NT_, 256, 0, stream>>>(x, t1b, mscale + (size_t)7 * D_, fnw, xnb, bg, gateb);
  gemmr<2>(xnb, wlmb, logits, NT_, V_, 1024, 1024, stream, idx, gateb, bh, bsc, ub);
}

// Round 14
// 1906.495 us; speedup vs baseline: 1.5408x; 1.5408x over previous
//
#include <hip/hip_runtime.h>
#include <hip/hip_bf16.h>
#include <cstdint>
#include <cstddef>

#define B_   2
#define S_   1024
#define V_   8192
#define D_   1024
#define H_   16
#define KVH_ 4
#define L_   8
#define HD_  64
#define KV_  256
#define HID_ 2736
#define HIDP 2752
#define NT_  (B_*S_)
#define EPSF 1.1920928955078125e-7f
#define SOFTCAPF 30.0f

typedef __bf16 bf8 __attribute__((ext_vector_type(8)));
typedef __bf16 bf4 __attribute__((ext_vector_type(4)));
typedef float  f4  __attribute__((ext_vector_type(4)));

// async global->LDS, 16B per lane; dst is wave-uniform base + lane*16
#define GLDS16(g, l) __builtin_amdgcn_global_load_lds( \
    (const __attribute__((address_space(1))) void*)(g), \
    (__attribute__((address_space(3))) void*)(l), 16, 0, 0)

// ---------------- wave / block reductions ----------------
__device__ __forceinline__ float wsum(float v){
#pragma unroll
  for (int m = 32; m >= 1; m >>= 1) v += __shfl_xor(v, m, 64);
  return v;
}
__device__ __forceinline__ float blocksum256(float v){
  __shared__ float red[4];
  v = wsum(v);
  if ((threadIdx.x & 63) == 0) red[threadIdx.x >> 6] = v;
  __syncthreads();
  return red[0] + red[1] + red[2] + red[3];
}
__device__ __forceinline__ float4 ld4b(const __bf16* p, size_t i4){
  bf4 v = ((const bf4*)p)[i4];
  return make_float4((float)v[0], (float)v[1], (float)v[2], (float)v[3]);
}

// ---------------- small-N GEMM (proven R10 path): BM x BN, BK=64, 4 waves ----------------
template<int BM, int BN, int OUT>
__global__ __launch_bounds__(256) void k_gemm(
    const __bf16* __restrict__ A, const __bf16* __restrict__ Wt,
    void* __restrict__ Cv, int M, int N, int K, int lda, int mtiles)
{
  constexpr int SMEM = (BM + BN) * 128;
  __shared__ __attribute__((aligned(16))) unsigned char smem[SMEM];
  __bf16* As = (__bf16*)smem;
  __bf16* Bs = (__bf16*)(smem + BM*128);

  const int tid  = threadIdx.x;
  const int nwg = gridDim.x;
  const int wg  = (blockIdx.x & 7) * (nwg >> 3) + (blockIdx.x >> 3);
  const int bm   = wg % mtiles;
  const int bn   = wg / mtiles;
  const int m0   = bm * BM, n0 = bn * BN;
  const int lane = tid & 63, wv = tid >> 6;
  const int wm   = (wv >> 1) * (BM / 2);
  const int wn   = (wv & 1) * (BN / 2);
  const int fr   = lane & 15, g = lane >> 4;
  constexpr int MI = BM / 32;
  constexpr int NJ = BN / 32;
  constexpr int AP = BM / 32;
  constexpr int BP = BN / 32;

  f4 acc[MI][NJ] = {};

  const int rs = lane >> 3, ss = lane & 7;
  const int cseg = ss ^ ((wv*8 + rs) & 7);
  const __bf16* aq[AP];
#pragma unroll
  for (int p = 0; p < AP; ++p)
    aq[p] = A + (size_t)(m0 + wv*8 + p*32 + rs) * lda + cseg*8;
  const __bf16* bq[BP];
#pragma unroll
  for (int p = 0; p < BP; ++p) {
    int rB = n0 + wv*8 + p*32 + rs; if (rB > N-1) rB = N-1;
    bq[p] = Wt + (size_t)rB * K + cseg*8;
  }

  for (int k0 = 0; k0 < K; k0 += 64) {
    __syncthreads();
#pragma unroll
    for (int p = 0; p < AP; ++p) GLDS16(aq[p] + k0, As + (wv*8 + p*32)*64);
#pragma unroll
    for (int p = 0; p < BP; ++p) GLDS16(bq[p] + k0, Bs + (wv*8 + p*32)*64);
    __syncthreads();

#pragma unroll
    for (int ks = 0; ks < 2; ++ks) {
      const int sgo = (((ks*4 + g) ^ (fr & 7)) << 3);
      bf8 af[MI], bf[NJ];
#pragma unroll
      for (int i = 0; i < MI; ++i)
        af[i] = *(const bf8*)&As[(wm + i*16 + fr)*64 + sgo];
#pragma unroll
      for (int j = 0; j < NJ; ++j)
        bf[j] = *(const bf8*)&Bs[(wn + j*16 + fr)*64 + sgo];
#pragma unroll
      for (int i = 0; i < MI; ++i)
#pragma unroll
        for (int j = 0; j < NJ; ++j)
          acc[i][j] = __builtin_amdgcn_mfma_f32_16x16x32_bf16(af[i], bf[j], acc[i][j], 0, 0, 0);
    }
  }

  const int rbase = g << 2;
#pragma unroll
  for (int i = 0; i < MI; ++i) {
    int gm = m0 + wm + i*16 + rbase;
#pragma unroll
    for (int j = 0; j < NJ; ++j) {
      int gn = n0 + wn + j*16 + fr;
      if (gn < N) {
        if constexpr (OUT == 1) {
#pragma unroll
          for (int r = 0; r < 4; ++r)
            ((__bf16*)Cv)[(size_t)(gm + r) * N + gn] = (__bf16)acc[i][j][r];
        } else {
#pragma unroll
          for (int r = 0; r < 4; ++r)
            ((float*)Cv)[(size_t)(gm + r) * N + gn] = acc[i][j][r];
        }
      }
    }
  }
}

// ---------------- 8-phase 256x256 GEMM: 8 waves, K-tiles of 32, 3 LDS buffers ----------------
#define STG8(t, h, b) do { \
    if ((h) < 2) { \
      const __bf16* _s = A + (size_t)(m0 + (h)*128 + w16 + rsub) * lda + (t)*32 + sseg*8; \
      GLDS16(_s, smem + (b)*32768 + ((h)*128 + w16) * 64); \
    } else { \
      int _rB = n0 + ((h)-2)*128 + w16 + rsub; if (_rB > N-1) _rB = N-1; \
      const __bf16* _s = Wt + (size_t)_rB * K + (t)*32 + sseg*8; \
      GLDS16(_s, smem + (b)*32768 + 16384 + (((h)-2)*128 + w16) * 64); \
    } } while (0)

#define LDA8(b, r, gg) (*(const bf8*)(smem + (b)*32768 + (r)*64 + (((gg) ^ ((((r)>>3)&1)<<1)))*16))
#define LDB8(b, r, gg) (*(const bf8*)(smem + (b)*32768 + 16384 + (r)*64 + (((gg) ^ ((((r)>>3)&1)<<1)))*16))

#define PH8(bt, q, dostage, st, sh, sb, W) do { \
    const int _r0 = wr*128 + ((q)>>1)*64 + fr; \
    const int _c0 = wc*64 + ((q)&1)*32 + fr; \
    bf8 _a0 = LDA8(bt, _r0 +  0, g); \
    bf8 _a1 = LDA8(bt, _r0 + 16, g); \
    bf8 _a2 = LDA8(bt, _r0 + 32, g); \
    bf8 _a3 = LDA8(bt, _r0 + 48, g); \
    bf8 _b0 = LDB8(bt, _c0 +  0, g); \
    bf8 _b1 = LDB8(bt, _c0 + 16, g); \
    if (dostage) STG8(st, sh, sb); \
    if ((W) == 4)      asm volatile("s_waitcnt vmcnt(4)" ::: "memory"); \
    else if ((W) == 0) asm volatile("s_waitcnt vmcnt(0)" ::: "memory"); \
    asm volatile("" ::: "memory"); \
    __builtin_amdgcn_s_barrier(); \
    asm volatile("" ::: "memory"); \
    __builtin_amdgcn_s_setprio(1); \
    acc[((q)>>1)*4+0][((q)&1)*2+0] = __builtin_amdgcn_mfma_f32_16x16x32_bf16(_a0, _b0, acc[((q)>>1)*4+0][((q)&1)*2+0], 0,0,0); \
    acc[((q)>>1)*4+0][((q)&1)*2+1] = __builtin_amdgcn_mfma_f32_16x16x32_bf16(_a0, _b1, acc[((q)>>1)*4+0][((q)&1)*2+1], 0,0,0); \
    acc[((q)>>1)*4+1][((q)&1)*2+0] = __builtin_amdgcn_mfma_f32_16x16x32_bf16(_a1, _b0, acc[((q)>>1)*4+1][((q)&1)*2+0], 0,0,0); \
    acc[((q)>>1)*4+1][((q)&1)*2+1] = __builtin_amdgcn_mfma_f32_16x16x32_bf16(_a1, _b1, acc[((q)>>1)*4+1][((q)&1)*2+1], 0,0,0); \
    acc[((q)>>1)*4+2][((q)&1)*2+0] = __builtin_amdgcn_mfma_f32_16x16x32_bf16(_a2, _b0, acc[((q)>>1)*4+2][((q)&1)*2+0], 0,0,0); \
    acc[((q)>>1)*4+2][((q)&1)*2+1] = __builtin_amdgcn_mfma_f32_16x16x32_bf16(_a2, _b1, acc[((q)>>1)*4+2][((q)&1)*2+1], 0,0,0); \
    acc[((q)>>1)*4+3][((q)&1)*2+0] = __builtin_amdgcn_mfma_f32_16x16x32_bf16(_a3, _b0, acc[((q)>>1)*4+3][((q)&1)*2+0], 0,0,0); \
    acc[((q)>>1)*4+3][((q)&1)*2+1] = __builtin_amdgcn_mfma_f32_16x16x32_bf16(_a3, _b1, acc[((q)>>1)*4+3][((q)&1)*2+1], 0,0,0); \
    __builtin_amdgcn_s_setprio(0); \
    asm volatile("" ::: "memory"); \
    __builtin_amdgcn_s_barrier(); \
    asm volatile("" ::: "memory"); \
  } while (0)

template<int OUT>
__global__ __launch_bounds__(512, 2) void k_gemm8(
    const __bf16* __restrict__ A, const __bf16* __restrict__ Wt,
    void* __restrict__ Cv, int M, int N, int K, int lda, int mtiles,
    const int* __restrict__ idx, const float* __restrict__ gateb,
    const float* __restrict__ bhd, const float* __restrict__ bsc,
    const float* __restrict__ ub)
{
  __shared__ __attribute__((aligned(16))) unsigned char smem[98304];
  const int tid = threadIdx.x;
  const int nwg = gridDim.x;
  const int wg  = (blockIdx.x & 7) * (nwg >> 3) + (blockIdx.x >> 3);
  const int bm = wg % mtiles, bnn = wg / mtiles;
  const int m0 = bm << 8, n0 = bnn << 8;
  const int l = tid & 63, wid = tid >> 6;
  const int wr = wid >> 2, wc = wid & 3;
  const int fr = l & 15, g = l >> 4;

  f4 acc[8][4] = {};

  const int w16  = wid * 16;
  const int rsub = l >> 2;
  const int sseg = (l & 3) ^ ((l >= 32) ? 2 : 0);

  const int nk = K >> 5;
  const int ni = nk >> 1;

  STG8(0, 0, 0); STG8(0, 1, 0); STG8(0, 2, 0); STG8(0, 3, 0);
  STG8(1, 0, 1); STG8(1, 1, 1); STG8(1, 2, 1); STG8(1, 3, 1);
  asm volatile("s_waitcnt vmcnt(4)" ::: "memory");
  asm volatile("" ::: "memory");
  __builtin_amdgcn_s_barrier();
  asm volatile("" ::: "memory");

  int b0 = 0;
  for (int i = 0; i < ni; ++i) {
    const int b1 = (b0 == 2) ? 0 : b0 + 1;
    const int b2 = (b1 == 2) ? 0 : b1 + 1;
    const bool nlast = (i + 1 < ni);
    const int t2 = 2*i + 2, t3 = 2*i + 3;
    PH8(b0, 0, nlast, t2, 0, b2, -1);
    PH8(b0, 1, nlast, t2, 1, b2, -1);
    PH8(b0, 2, nlast, t2, 2, b2, -1);
    PH8(b0, 3, nlast, t2, 3, b2, nlast ? 4 : 0);
    PH8(b1, 0, nlast, t3, 0, b0, -1);
    PH8(b1, 1, nlast, t3, 1, b0, -1);
    PH8(b1, 2, nlast, t3, 2, b0, -1);
    PH8(b1, 3, nlast, t3, 3, b0, nlast ? 4 : -1);
    b0 = b2;
  }

  if constexpr (OUT == 1) {
    __bf16* C = (__bf16*)Cv;
#pragma unroll
    for (int ii = 0; ii < 8; ++ii) {
      int gm = m0 + wr*128 + ii*16 + g*4;
#pragma unroll
      for (int j = 0; j < 4; ++j) {
        int gn = n0 + wc*64 + j*16 + fr;
        if (gn < N) {
#pragma unroll
          for (int r = 0; r < 4; ++r)
            C[(size_t)(gm + r) * N + gn] = (__bf16)acc[ii][j][r];
        }
      }
    }
  } else {
    float* EP = (float*)smem;
    __syncthreads();
#pragma unroll
    for (int pass = 0; pass < 4; ++pass) {
      if (wr == (pass >> 1)) {
#pragma unroll
        for (int a = 0; a < 4; ++a) {
          int ii = (pass & 1)*4 + a;
#pragma unroll
          for (int j = 0; j < 4; ++j)
#pragma unroll
            for (int r = 0; r < 4; ++r)
              EP[(a*16 + g*4 + r)*256 + wc*64 + j*16 + fr] = acc[ii][j][r];
        }
      }
      __syncthreads();
#pragma unroll
      for (int it = 0; it < 8; ++it) {
        int row = it*8 + (tid >> 6);
        int c0  = (tid & 63) << 2;
        int grow = m0 + pass*64 + row;
        int gn = n0 + c0;
        float gt = gateb[grow];
        int tk = idx[grow];
        float4 a4 = *(float4*)&EP[row*256 + c0];
        float4 b4 = *(const float4*)&bhd[(size_t)tk * V_ + gn];
        float4 u4 = *(const float4*)&ub[gn];
        float4 s4 = *(const float4*)&bsc[gn];
        float4 o;
        o.x = SOFTCAPF * tanhf((a4.x + u4.x + gt*b4.x*s4.x) / SOFTCAPF);
        o.y = SOFTCAPF * tanhf((a4.y + u4.y + gt*b4.y*s4.y) / SOFTCAPF);
        o.z = SOFTCAPF * tanhf((a4.z + u4.z + gt*b4.z*s4.z) / SOFTCAPF);
        o.w = SOFTCAPF * tanhf((a4.w + u4.w + gt*b4.w*s4.w) / SOFTCAPF);
        *(float4*)&((float*)Cv)[(size_t)grow * N + gn] = o;
      }
      __syncthreads();
    }
  }
}
#undef PH8
#undef LDA8
#undef LDB8
#undef STG8

// ---------------- weight f32 -> bf16 convert ----------------
__global__ void k_cvt(const float* __restrict__ s, __bf16* __restrict__ d,
                      int perL, int K, int Kpad, long dstL, long dstOff, long nd4)
{
  long i = (long)blockIdx.x * 256 + threadIdx.x;
  if (i >= nd4) return;
  const int kp4 = Kpad >> 2;
  long row = i / kp4;
  int  c   = (int)(i % kp4) << 2;
  long layer = row / perL, r = row % perL;
  bf4 o;
  if (c < K) {
    float4 v = *(const float4*)(s + (layer*perL + r) * (long)K + c);
    o[0] = (__bf16)v.x; o[1] = (__bf16)v.y; o[2] = (__bf16)v.z; o[3] = (__bf16)v.w;
  } else { o[0] = o[1] = o[2] = o[3] = (__bf16)0.f; }
  *(bf4*)(d + layer*dstL + dstOff + (long)r*Kpad + c) = o;
}

// ---------------- embedding + rmsnorm ----------------
__global__ void k_embed(const int* __restrict__ idx, const float* __restrict__ emb,
                        const float* __restrict__ wn, float* __restrict__ x, float* __restrict__ x0)
{
  const int r = blockIdx.x, t = threadIdx.x;
  const float4 v = ((const float4*)(emb + (size_t)idx[r] * D_))[t];
  float ss = blocksum256(v.x*v.x + v.y*v.y + v.z*v.z + v.w*v.w);
  float rs = rsqrtf(ss / (float)D_ + EPSF);
  const float4 w = ((const float4*)wn)[t];
  float4 o = make_float4(v.x*rs*w.x, v.y*rs*w.y, v.z*rs*w.z, v.w*rs*w.w);
  ((float4*)(x  + (size_t)r * D_))[t] = o;
  ((float4*)(x0 + (size_t)r * D_))[t] = o;
}

// ---------------- block start: [x += msc*t1] [skip store] [skip add] mix + norm ----------------
__global__ void k_blockstart(
    float* __restrict__ x, const float* __restrict__ x0,
    const __bf16* __restrict__ t1, const float* __restrict__ msc,
    float* __restrict__ skstore, const float* __restrict__ skread, int same,
    const float* __restrict__ skw, const float* __restrict__ skg,
    const float* __restrict__ mix, const float* __restrict__ nw,
    __bf16* __restrict__ xn)
{
  const int r = blockIdx.x, t = threadIdx.x;
  const size_t i4 = (size_t)r * 256 + t;
  float4 xv = ((float4*)x)[i4];
  if (t1) {
    float4 tv = ld4b(t1, i4);
    float4 s  = ((const float4*)msc)[t];
    xv.x += s.x*tv.x; xv.y += s.y*tv.y; xv.z += s.z*tv.z; xv.w += s.w*tv.w;
  }
  if (skstore) ((float4*)skstore)[i4] = xv;
  if (skw) {
    float4 sv;
    if (same) sv = xv;
    else      sv = ((const float4*)skread)[i4];
    float4 w = ((const float4*)skw)[t];
    float4 g = ((const float4*)skg)[t];
    xv.x += w.x / (1.f + __expf(-g.x)) * sv.x;
    xv.y += w.y / (1.f + __expf(-g.y)) * sv.y;
    xv.z += w.z / (1.f + __expf(-g.z)) * sv.z;
    xv.w += w.w / (1.f + __expf(-g.w)) * sv.w;
  }
  float4 x0v = ((const float4*)x0)[i4];
  float4 m0  = ((const float4*)mix)[t];
  float4 m1  = ((const float4*)(mix + D_))[t];
  float4 nv;
  nv.x = m0.x*xv.x + m1.x*x0v.x; nv.y = m0.y*xv.y + m1.y*x0v.y;
  nv.z = m0.z*xv.z + m1.z*x0v.z; nv.w = m0.w*xv.w + m1.w*x0v.w;
  ((float4*)x)[i4] = nv;
  float ss = blocksum256(nv.x*nv.x + nv.y*nv.y + nv.z*nv.z + nv.w*nv.w);
  float rs = rsqrtf(ss / (float)D_ + EPSF);
  const float4 w = ((const float4*)nw)[t];
  bf4 o = { (__bf16)(nv.x*rs*w.x), (__bf16)(nv.y*rs*w.y),
            (__bf16)(nv.z*rs*w.z), (__bf16)(nv.w*rs*w.w) };
  ((bf4*)xn)[i4] = o;
}

// ---------------- x += sc*t1 ; xn = bf16(rmsnorm(x)*nw) ; optional bigram gate ----------------
__global__ void k_addnorm(float* __restrict__ x, const __bf16* __restrict__ t1,
                          const float* __restrict__ sc, const float* __restrict__ nw,
                          __bf16* __restrict__ xn,
                          const float* __restrict__ bg, float* __restrict__ gateb)
{
  const int r = blockIdx.x, t = threadIdx.x;
  const size_t i4 = (size_t)r * 256 + t;
  float4 xv = ((float4*)x)[i4];
  float4 tv = ld4b(t1, i4);
  float4 s  = ((const float4*)sc)[t];
  xv.x += s.x*tv.x; xv.y += s.y*tv.y; xv.z += s.z*tv.z; xv.w += s.w*tv.w;
  ((float4*)x)[i4] = xv;
  float ss = blocksum256(xv.x*xv.x + xv.y*xv.y + xv.z*xv.z + xv.w*xv.w);
  float rs = rsqrtf(ss / (float)D_ + EPSF);
  const float4 w = ((const float4*)nw)[t];
  float ox = xv.x*rs*w.x, oy = xv.y*rs*w.y, oz = xv.z*rs*w.z, ow = xv.w*rs*w.w;
  bf4 o = { (__bf16)ox, (__bf16)oy, (__bf16)oz, (__bf16)ow };
  ((bf4*)xn)[i4] = o;
  if (bg) {
    float4 b4 = ((const float4*)bg)[t];
    float gd = ox*b4.x + oy*b4.y + oz*b4.z + ow*b4.w;
    __syncthreads();
    float gs = blocksum256(gd);
    if (t == 0) gateb[r] = 1.f / (1.f + __expf(-gs));
  }
}

// ---------------- rmsnorm D=1024, f32 in -> bf16 out ----------------
__global__ void k_rmsnormb(const float* __restrict__ in, const float* __restrict__ w,
                           __bf16* __restrict__ out)
{
  const int r = blockIdx.x, t = threadIdx.x;
  float4 v = ((const float4*)(in + (size_t)r * D_))[t];
  float ss = blocksum256(v.x*v.x + v.y*v.y + v.z*v.z + v.w*v.w);
  float rs = rsqrtf(ss / (float)D_ + EPSF);
  const float4 w4 = ((const float4*)w)[t];
  bf4 o = { (__bf16)(v.x*rs*w4.x), (__bf16)(v.y*rs*w4.y),
            (__bf16)(v.z*rs*w4.z), (__bf16)(v.w*rs*w4.w) };
  ((bf4*)(out + (size_t)r * D_))[t] = o;
}

// ---------------- dwconv helper (bf16 strided buffer) ----------------
__device__ __forceinline__ float conv3b(const __bf16* buf, int tok, int s, int ld, int col,
                                        const float* w, int C, int c){
  const __bf16* p0 = buf + (size_t)tok * ld + col;
  float a  = (s >= 2) ? (float)p0[-2*ld] : 0.f;
  float bb = (s >= 1) ? (float)p0[-ld]   : 0.f;
  return w[c]*a + w[C + c]*bb + w[2*C + c]*(float)p0[0];
}

// ---------------- QKV prep: dwconv + head-rmsnorm + RoPE + q_gain -> bf16 (256 thr) ----------------
__global__ __launch_bounds__(256) void k_prep(
    const __bf16* __restrict__ qkv,
    const float* __restrict__ qcw, const float* __restrict__ kcw, const float* __restrict__ vcw,
    const float* __restrict__ qgain,
    __bf16* __restrict__ q2, __bf16* __restrict__ k2, __bf16* __restrict__ v2)
{
  const int tok = blockIdx.x;
  const int s = tok & (S_ - 1);
  const int t = threadIdx.x, lane = t & 63, w = t >> 6;
  __shared__ float qsh[1024];

  const int j = lane & 31;
  float freq = __expf(-(float)j * (9.210340371976184f / 32.f));
  float sn, cs;
  __sincosf((float)s * freq, &sn, &cs);

#pragma unroll
  for (int k = 0; k < 4; ++k) {
    int c = t + k*256;
    float qc = conv3b(qkv, tok, s, 1536, c, qcw, D_, c);
    float ssq = wsum(qc * qc);
    float qn = qc * rsqrtf(ssq / 64.f + EPSF);
    float pr = __shfl_xor(qn, 32, 64);
    qsh[c] = qn * cs + ((lane < 32) ? pr * sn : -pr * sn);
  }
  __syncthreads();
  float qg[16];
#pragma unroll
  for (int g = 0; g < 16; ++g) qg[g] = qsh[g*64 + lane];
#pragma unroll
  for (int k = 0; k < 4; ++k) {
    int h = (k << 2) + w;
    float acc = 0.f;
#pragma unroll
    for (int g = 0; g < 16; ++g) acc += qgain[h*16 + g] * qg[g];
    q2[(size_t)tok * D_ + h*64 + lane] = (__bf16)acc;
  }

  {
    float kc = conv3b(qkv, tok, s, 1536, 1024 + t, kcw, KV_, t);
    float ssk = wsum(kc * kc);
    float kn = kc * rsqrtf(ssk / 64.f + EPSF);
    float pk = __shfl_xor(kn, 32, 64);
    k2[(size_t)tok * KV_ + t] = (__bf16)(kn * cs + ((lane < 32) ? pk * sn : -pk * sn));
  }
  v2[(size_t)tok * KV_ + t] = (__bf16)conv3b(qkv, tok, s, 1536, 1280 + t, vcw, KV_, t);
}

// ---------------- MFMA flash attention (bf16 compute, f32 accumulate) ----------------
// qb-flip load balance: co-resident block pair (id, id+256) differs only in b,
// so flipping qb for b=1 gives each CU pair total work qb + (15-qb) = const.
#define LDK 72
__global__ __launch_bounds__(256) void k_attn(
    const __bf16* __restrict__ q2, const __bf16* __restrict__ k2,
    const __bf16* __restrict__ v2, float* __restrict__ y)
{
  __shared__ __attribute__((aligned(16))) __bf16 Ks[64*LDK];
  __shared__ __attribute__((aligned(16))) __bf16 Vt[64*LDK];
  __shared__ __attribute__((aligned(16))) __bf16 Ps[4][16*LDK];

  const int id = blockIdx.x;
  const int h  = (id >> 4) & 15;
  const int b  = id >> 8;
  const int qb = b ? (15 - (id & 15)) : (id & 15);   // load-balance flip
  const int tid = threadIdx.x, l = tid & 63, wq = tid >> 6;
  const int g = l >> 4, fr = l & 15;
  const int kvh = h >> 2;
  const int qrow = qb*64 + wq*16 + fr;

  bf8 qf[2];
#pragma unroll
  for (int ks = 0; ks < 2; ++ks)
    qf[ks] = *(const bf8*)&q2[(size_t)(b*S_ + qrow)*D_ + h*64 + g*8 + ks*32];

  float m = -1e30f, lsum = 0.f;
  f4 acc[4] = {};

  const int nch = qb + 1;
  for (int ch = 0; ch < nch; ++ch) {
    const int t0 = ch << 6;
    __syncthreads();
#pragma unroll
    for (int it = 0; it < 2; ++it) {
      int i = tid + it*256;
      int row = i >> 3, seg = (i & 7) << 3;
      *(bf8*)&Ks[row*LDK + seg] =
        *(const bf8*)&k2[(size_t)(b*S_ + t0 + row)*KV_ + kvh*64 + seg];
    }
    {
      int key4 = (tid & 15) << 2, hd4 = (tid >> 4) << 2;
      bf4 vv[4];
#pragma unroll
      for (int kk = 0; kk < 4; ++kk)
        vv[kk] = *(const bf4*)&v2[(size_t)(b*S_ + t0 + key4 + kk)*KV_ + kvh*64 + hd4];
#pragma unroll
      for (int hh = 0; hh < 4; ++hh) {
        bf4 w = { vv[0][hh], vv[1][hh], vv[2][hh], vv[3][hh] };
        *(bf4*)&Vt[(hd4 + hh)*LDK + key4] = w;
      }
    }
    __syncthreads();

    f4 sc[4] = {};
#pragma unroll
    for (int ks = 0; ks < 2; ++ks)
#pragma unroll
      for (int t = 0; t < 4; ++t) {
        bf8 kf = *(const bf8*)&Ks[(t*16 + fr)*LDK + g*8 + ks*32];
        sc[t] = __builtin_amdgcn_mfma_f32_16x16x32_bf16(kf, qf[ks], sc[t], 0, 0, 0);
      }

    const bool lastch = (ch == qb);
    float s[4][4];
    float pmax = -1e30f;
#pragma unroll
    for (int t = 0; t < 4; ++t)
#pragma unroll
      for (int r = 0; r < 4; ++r) {
        float v = sc[t][r] * 0.125f;
        if (lastch && (t0 + t*16 + g*4 + r > qrow)) v = -1e30f;
        s[t][r] = v;
        pmax = fmaxf(pmax, v);
      }
    pmax = fmaxf(pmax, __shfl_xor(pmax, 16, 64));
    pmax = fmaxf(pmax, __shfl_xor(pmax, 32, 64));
    float mnew = fmaxf(m, pmax);
    float alpha = __expf(m - mnew);
    float rs = 0.f;
#pragma unroll
    for (int t = 0; t < 4; ++t)
#pragma unroll
      for (int r = 0; r < 4; ++r) { float p = __expf(s[t][r] - mnew); s[t][r] = p; rs += p; }
    rs += __shfl_xor(rs, 16, 64);
    rs += __shfl_xor(rs, 32, 64);
    lsum = lsum * alpha + rs;
    m = mnew;
#pragma unroll
    for (int t = 0; t < 4; ++t) acc[t] = acc[t] * alpha;

#pragma unroll
    for (int t = 0; t < 4; ++t) {
      bf4 pw = { (__bf16)s[t][0], (__bf16)s[t][1], (__bf16)s[t][2], (__bf16)s[t][3] };
      *(bf4*)&Ps[wq][fr*LDK + t*16 + g*4] = pw;
    }

#pragma unroll
    for (int ks = 0; ks < 2; ++ks) {
      bf8 pf = *(const bf8*)&Ps[wq][fr*LDK + g*8 + ks*32];
#pragma unroll
      for (int t = 0; t < 4; ++t) {
        bf8 vf = *(const bf8*)&Vt[(t*16 + fr)*LDK + g*8 + ks*32];
        acc[t] = __builtin_amdgcn_mfma_f32_16x16x32_bf16(vf, pf, acc[t], 0, 0, 0);
      }
    }
  }

  float inv = 1.f / lsum;
#pragma unroll
  for (int t = 0; t < 4; ++t)
#pragma unroll
    for (int r = 0; r < 4; ++r)
      y[(size_t)(b*S_ + qrow)*D_ + h*64 + t*16 + g*4 + r] = acc[t][r] * inv;
}

// ---------------- fused silu*mul + dwconv + rmsnorm -> bf16 (reads bf16 hb) ----------------
__device__ __forceinline__ float hprodb(const __bf16* row, int c){
  float a = (float)row[c], b = (float)row[HID_ + c];
  return a * b / (1.f + __expf(-b));
}
__global__ __launch_bounds__(256) void k_hfuse(
    const __bf16* __restrict__ hb, const float* __restrict__ cw,
    const float* __restrict__ nw, __bf16* __restrict__ out)
{
  const int tok = blockIdx.x, t = threadIdx.x;
  const int s = tok & (S_ - 1);
  const __bf16* row0 = hb + (size_t)tok * 5472;
  float v[11]; float ss = 0.f;
#pragma unroll
  for (int ii = 0; ii < 11; ++ii) {
    int c = t + ii*256;
    float cv = 0.f;
    if (c < HID_) {
      float p0 = hprodb(row0, c);
      float p1 = (s >= 1) ? hprodb(row0 - 5472, c) : 0.f;
      float p2 = (s >= 2) ? hprodb(row0 - 2*5472, c) : 0.f;
      cv = cw[c]*p2 + cw[HID_ + c]*p1 + cw[2*HID_ + c]*p0;
    }
    v[ii] = cv; ss += cv*cv;
  }
  ss = blocksum256(ss);
  float rs = rsqrtf(ss / (float)HID_ + EPSF);
#pragma unroll
  for (int ii = 0; ii < 11; ++ii) {
    int c = t + ii*256;
    if (c < HIDP)
      out[(size_t)tok * HIDP + c] = (c < HID_) ? (__bf16)(v[ii]*rs*nw[c]) : (__bf16)0.f;
  }
}

// ---------------- host ----------------
template<int BM, int BN, int OUT>
static inline void gemm(const __bf16* A, const __bf16* W, void* C, int M, int N, int K,
                        int lda, hipStream_t s)
{
  int mt = M / BM, nt = (N + BN - 1) / BN;
  k_gemm<BM, BN, OUT><<<dim3(mt * nt), dim3(256), 0, s>>>(A, W, C, M, N, K, lda, mt);
}

template<int OUT>
static inline void gemm8(const __bf16* A, const __bf16* W, void* C, int M, int N, int K,
                         int lda, hipStream_t s,
                         const int* idx = nullptr, const float* gateb = nullptr,
                         const float* bhd = nullptr, const float* bsc = nullptr,
                         const float* ub = nullptr)
{
  int mt = M >> 8, nt = (N + 255) >> 8;
  k_gemm8<OUT><<<dim3(mt * nt), dim3(512), 0, s>>>(A, W, C, M, N, K, lda, mt,
                                                   idx, gateb, bhd, bsc, ub);
}

extern "C" void kernel_launch(void* const* d_in, const int* in_sizes, int n_in,
                              void* d_out, int out_size, void* d_ws, size_t ws_size,
                              hipStream_t stream)
{
  const int*   idx    = (const int*)d_in[0];
  const float* temb   = (const float*)d_in[1];
  const float* enw    = (const float*)d_in[2];
  const float* rmix   = (const float*)d_in[3];
  const float* anw    = (const float*)d_in[4];
  const float* mnw    = (const float*)d_in[5];
  const float* ascale = (const float*)d_in[6];
  const float* mscale = (const float*)d_in[7];
  const float* Wq     = (const float*)d_in[8];
  const float* Wk     = (const float*)d_in[9];
  const float* Wv     = (const float*)d_in[10];
  const float* qcw    = (const float*)d_in[11];
  const float* kcw    = (const float*)d_in[12];
  const float* vcw    = (const float*)d_in[13];
  const float* qgain  = (const float*)d_in[14];
  const float* panw   = (const float*)d_in[15];
  const float* Wo     = (const float*)d_in[16];
  const float* Wfc    = (const float*)d_in[17];
  const float* Wgate  = (const float*)d_in[18];
  const float* hcw    = (const float*)d_in[19];
  const float* hnw    = (const float*)d_in[20];
  const float* Wmp    = (const float*)d_in[21];
  const float* skw    = (const float*)d_in[22];
  const float* skg    = (const float*)d_in[23];
  const float* fnw    = (const float*)d_in[24];
  const float* lmw    = (const float*)d_in[25];
  const float* bh     = (const float*)d_in[26];
  const float* bsc    = (const float*)d_in[27];
  const float* bg     = (const float*)d_in[28];
  const float* ub     = (const float*)d_in[29];

  float* p = (float*)d_ws;
  float* x    = p; p += (size_t)NT_ * D_;
  float* x0   = p; p += (size_t)NT_ * D_;
  float* y    = p; p += (size_t)NT_ * D_;
  float* skips= p; p += (size_t)4 * NT_ * D_;
  float* gateb= p; p += NT_;
  __bf16* qkvb= (__bf16*)p; p += (size_t)NT_ * 1536 / 2;
  __bf16* hbb = (__bf16*)p; p += (size_t)NT_ * 5472 / 2;
  __bf16* t1b = (__bf16*)p; p += (size_t)NT_ * D_ / 2;
  __bf16* xnb = (__bf16*)p; p += (size_t)NT_ * D_ / 2;
  __bf16* q2b = (__bf16*)p; p += (size_t)NT_ * D_ / 2;
  __bf16* k2b = (__bf16*)p; p += (size_t)NT_ * KV_ / 2;
  __bf16* v2b = (__bf16*)p; p += (size_t)NT_ * KV_ / 2;
  __bf16* hnb = (__bf16*)p; p += (size_t)NT_ * HIDP / 2;
  __bf16* wqkv= (__bf16*)p; p += (size_t)L_ * 1536 * 1024 / 2;
  __bf16* wob = (__bf16*)p; p += (size_t)L_ * 1024 * 1024 / 2;
  __bf16* wfcg= (__bf16*)p; p += (size_t)L_ * 5472 * 1024 / 2;
  __bf16* wmpb= (__bf16*)p; p += (size_t)L_ * 1024 * HIDP / 2;
  __bf16* wlmb= (__bf16*)p; p += (size_t)V_ * 1024 / 2;
  float* logits = (float*)d_out;

  // ---- weight conversions (every launch; deterministic) ----
  auto cvt = [&](const float* s, __bf16* d, int perL, int K, int Kpad,
                 long dstL, long dstOff, int nl) {
    long nd4 = (long)nl * perL * (Kpad >> 2);
    int grid = (int)((nd4 + 255) / 256);
    k_cvt<<<grid, 256, 0, stream>>>(s, d, perL, K, Kpad, dstL, dstOff, nd4);
  };
  cvt(Wq,    wqkv, 1024, 1024, 1024, 1536L*1024, 0,          L_);
  cvt(Wk,    wqkv,  256, 1024, 1024, 1536L*1024, 1024L*1024, L_);
  cvt(Wv,    wqkv,  256, 1024, 1024, 1536L*1024, 1280L*1024, L_);
  cvt(Wo,    wob,  1024, 1024, 1024, 1024L*1024, 0,          L_);
  cvt(Wfc,   wfcg, 2736, 1024, 1024, 5472L*1024, 0,          L_);
  cvt(Wgate, wfcg, 2736, 1024, 1024, 5472L*1024, 2736L*1024, L_);
  cvt(Wmp,   wmpb, 1024, 2736, HIDP, 1024L*HIDP, 0,          L_);
  cvt(lmw,   wlmb, 8192, 1024, 1024, 8192L*1024, 0,          1);

  k_embed<<<NT_, 256, 0, stream>>>(idx, temb, enw, x, x0);

  for (int i = 0; i < L_; ++i) {
    const float* pmsc = (i > 0) ? mscale + (size_t)(i-1) * D_ : nullptr;
    float* skst = (i >= 1 && i <= 4) ? skips + (size_t)(i-1) * NT_ * D_ : nullptr;
    const float* skrd = (i >= 4) ? skips + (size_t)(7-i) * NT_ * D_ : nullptr;
    const float* swp = (i >= 4) ? skw + (size_t)(i-4) * D_ : nullptr;
    const float* sgp = (i >= 4) ? skg + (size_t)(i-4) * D_ : nullptr;
    k_blockstart<<<NT_, 256, 0, stream>>>(x, x0, (i > 0) ? t1b : nullptr, pmsc,
                                          skst, skrd, (i == 4) ? 1 : 0, swp, sgp,
                                          rmix + (size_t)i * 2 * D_,
                                          anw + (size_t)i * D_, xnb);
    gemm<64, 128, 1>(xnb, wqkv + (size_t)i * 1536 * 1024, qkvb, NT_, 1536, 1024, 1024, stream);
    k_prep<<<NT_, 256, 0, stream>>>(qkvb,
                                    qcw + (size_t)i * 3 * D_, kcw + (size_t)i * 3 * KV_,
                                    vcw + (size_t)i * 3 * KV_, qgain + (size_t)i * H_ * H_,
                                    q2b, k2b, v2b);
    k_attn<<<B_ * H_ * (S_/64), 256, 0, stream>>>(q2b, k2b, v2b, y);
    k_rmsnormb<<<NT_, 256, 0, stream>>>(y, panw + (size_t)i * D_, xnb);
    gemm<64, 64, 1>(xnb, wob + (size_t)i * 1024 * 1024, t1b, NT_, 1024, 1024, 1024, stream);
    k_addnorm<<<NT_, 256, 0, stream>>>(x, t1b, ascale + (size_t)i * D_,
                                       mnw + (size_t)i * D_, xnb, nullptr, nullptr);
    gemm8<1>(xnb, wfcg + (size_t)i * 5472 * 1024, hbb, NT_, 5472, 1024, 1024, stream);
    k_hfuse<<<NT_, 256, 0, stream>>>(hbb, hcw + (size_t)i * 3 * HID_,
                                     hnw + (size_t)i * HID_, hnb);
    gemm<64, 64, 1>(hnb, wmpb + (size_t)i * 1024 * HIDP, t1b, NT_, 1024, HIDP, HIDP, stream);
  }

  // final: mlp7 residual + final norm + bigram gate
  k_addnorm<<<NT_, 256, 0, stream>>>(x, t1b, mscale + (size_t)7 * D_, fnw, xnb, bg, gateb);
  gemm8<2>(xnb, wlmb, logits, NT_, V_, 1024, 1024, stream, idx, gateb, bh, bsc, ub);
}

// Round 15
// 1682.941 us; speedup vs baseline: 1.7455x; 1.1328x over previous
//
#include <hip/hip_runtime.h>
#include <hip/hip_bf16.h>
#include <cstdint>
#include <cstddef>

#define B_   2
#define S_   1024
#define V_   8192
#define D_   1024
#define H_   16
#define KVH_ 4
#define L_   8
#define HD_  64
#define KV_  256
#define HID_ 2736
#define HIDP 2816
#define NT_  (B_*S_)
#define EPSF 1.1920928955078125e-7f
#define SOFTCAPF 30.0f

typedef __bf16 bf8 __attribute__((ext_vector_type(8)));
typedef __bf16 bf4 __attribute__((ext_vector_type(4)));
typedef float  f4  __attribute__((ext_vector_type(4)));

// async global->LDS, 16B per lane; dst is wave-uniform base + lane*16
#define GLDS16(g, l) __builtin_amdgcn_global_load_lds( \
    (const __attribute__((address_space(1))) void*)(g), \
    (__attribute__((address_space(3))) void*)(l), 16, 0, 0)

// ---------------- wave / block reductions ----------------
__device__ __forceinline__ float wsum(float v){
#pragma unroll
  for (int m = 32; m >= 1; m >>= 1) v += __shfl_xor(v, m, 64);
  return v;
}
__device__ __forceinline__ float blocksum256(float v){
  __shared__ float red[4];
  v = wsum(v);
  if ((threadIdx.x & 63) == 0) red[threadIdx.x >> 6] = v;
  __syncthreads();
  return red[0] + red[1] + red[2] + red[3];
}
__device__ __forceinline__ float4 ld4b(const __bf16* p, size_t i4){
  bf4 v = ((const bf4*)p)[i4];
  return make_float4((float)v[0], (float)v[1], (float)v[2], (float)v[3]);
}

// ---------------- small-N GEMM: BM x BN, BK=64, 4 waves, optional split-K=2 ----------------
// Split-K: kz = wg&1 computes K-half kz, writing bf16 partial to Cv + kz*M*N.
// Consumers sum the two partial planes (deterministic, no atomics).
template<int BM, int BN, int OUT, int SK>
__global__ __launch_bounds__(256) void k_gemm(
    const __bf16* __restrict__ A, const __bf16* __restrict__ Wt,
    void* __restrict__ Cv, int M, int N, int K, int lda, int mtiles)
{
  constexpr int SMEM = (BM + BN) * 128;
  __shared__ __attribute__((aligned(16))) unsigned char smem[SMEM];
  __bf16* As = (__bf16*)smem;
  __bf16* Bs = (__bf16*)(smem + BM*128);

  const int tid  = threadIdx.x;
  const int nwg = gridDim.x;
  const int wg  = (blockIdx.x & 7) * (nwg >> 3) + (blockIdx.x >> 3);
  const int kz   = (SK == 2) ? (wg & 1) : 0;
  const int wgt  = (SK == 2) ? (wg >> 1) : wg;
  const int bm   = wgt % mtiles;
  const int bn   = wgt / mtiles;
  const int m0   = bm * BM, n0 = bn * BN;
  const int Keff = K / SK;
  const int koff = kz * Keff;
  const int lane = tid & 63, wv = tid >> 6;
  const int wm   = (wv >> 1) * (BM / 2);
  const int wn   = (wv & 1) * (BN / 2);
  const int fr   = lane & 15, g = lane >> 4;
  constexpr int MI = BM / 32;
  constexpr int NJ = BN / 32;
  constexpr int AP = BM / 32;
  constexpr int BP = BN / 32;

  f4 acc[MI][NJ] = {};

  const int rs = lane >> 3, ss = lane & 7;
  const int cseg = ss ^ ((wv*8 + rs) & 7);
  const __bf16* aq[AP];
#pragma unroll
  for (int p = 0; p < AP; ++p)
    aq[p] = A + (size_t)(m0 + wv*8 + p*32 + rs) * lda + koff + cseg*8;
  const __bf16* bq[BP];
#pragma unroll
  for (int p = 0; p < BP; ++p) {
    int rB = n0 + wv*8 + p*32 + rs; if (rB > N-1) rB = N-1;
    bq[p] = Wt + (size_t)rB * K + koff + cseg*8;
  }

  for (int k0 = 0; k0 < Keff; k0 += 64) {
    __syncthreads();
#pragma unroll
    for (int p = 0; p < AP; ++p) GLDS16(aq[p] + k0, As + (wv*8 + p*32)*64);
#pragma unroll
    for (int p = 0; p < BP; ++p) GLDS16(bq[p] + k0, Bs + (wv*8 + p*32)*64);
    __syncthreads();

#pragma unroll
    for (int ks = 0; ks < 2; ++ks) {
      const int sgo = (((ks*4 + g) ^ (fr & 7)) << 3);
      bf8 af[MI], bf[NJ];
#pragma unroll
      for (int i = 0; i < MI; ++i)
        af[i] = *(const bf8*)&As[(wm + i*16 + fr)*64 + sgo];
#pragma unroll
      for (int j = 0; j < NJ; ++j)
        bf[j] = *(const bf8*)&Bs[(wn + j*16 + fr)*64 + sgo];
#pragma unroll
      for (int i = 0; i < MI; ++i)
#pragma unroll
        for (int j = 0; j < NJ; ++j)
          acc[i][j] = __builtin_amdgcn_mfma_f32_16x16x32_bf16(af[i], bf[j], acc[i][j], 0, 0, 0);
    }
  }

  const int rbase = g << 2;
  __bf16* Cb = (__bf16*)Cv + (size_t)kz * M * N;
#pragma unroll
  for (int i = 0; i < MI; ++i) {
    int gm = m0 + wm + i*16 + rbase;
#pragma unroll
    for (int j = 0; j < NJ; ++j) {
      int gn = n0 + wn + j*16 + fr;
      if (gn < N) {
#pragma unroll
        for (int r = 0; r < 4; ++r)
          Cb[(size_t)(gm + r) * N + gn] = (__bf16)acc[i][j][r];
      }
    }
  }
}

// ---------------- 8-phase 256x256 GEMM: 8 waves, K-tiles of 32, 3 LDS buffers ----------------
#define STG8(t, h, b) do { \
    if ((h) < 2) { \
      const __bf16* _s = A + (size_t)(m0 + (h)*128 + w16 + rsub) * lda + (t)*32 + sseg*8; \
      GLDS16(_s, smem + (b)*32768 + ((h)*128 + w16) * 64); \
    } else { \
      int _rB = n0 + ((h)-2)*128 + w16 + rsub; if (_rB > N-1) _rB = N-1; \
      const __bf16* _s = Wt + (size_t)_rB * K + (t)*32 + sseg*8; \
      GLDS16(_s, smem + (b)*32768 + 16384 + (((h)-2)*128 + w16) * 64); \
    } } while (0)

#define LDA8(b, r, gg) (*(const bf8*)(smem + (b)*32768 + (r)*64 + (((gg) ^ ((((r)>>3)&1)<<1)))*16))
#define LDB8(b, r, gg) (*(const bf8*)(smem + (b)*32768 + 16384 + (r)*64 + (((gg) ^ ((((r)>>3)&1)<<1)))*16))

#define PH8(bt, q, dostage, st, sh, sb, W) do { \
    const int _r0 = wr*128 + ((q)>>1)*64 + fr; \
    const int _c0 = wc*64 + ((q)&1)*32 + fr; \
    bf8 _a0 = LDA8(bt, _r0 +  0, g); \
    bf8 _a1 = LDA8(bt, _r0 + 16, g); \
    bf8 _a2 = LDA8(bt, _r0 + 32, g); \
    bf8 _a3 = LDA8(bt, _r0 + 48, g); \
    bf8 _b0 = LDB8(bt, _c0 +  0, g); \
    bf8 _b1 = LDB8(bt, _c0 + 16, g); \
    if (dostage) STG8(st, sh, sb); \
    if ((W) == 4)      asm volatile("s_waitcnt vmcnt(4)" ::: "memory"); \
    else if ((W) == 0) asm volatile("s_waitcnt vmcnt(0)" ::: "memory"); \
    asm volatile("" ::: "memory"); \
    __builtin_amdgcn_s_barrier(); \
    asm volatile("" ::: "memory"); \
    __builtin_amdgcn_s_setprio(1); \
    acc[((q)>>1)*4+0][((q)&1)*2+0] = __builtin_amdgcn_mfma_f32_16x16x32_bf16(_a0, _b0, acc[((q)>>1)*4+0][((q)&1)*2+0], 0,0,0); \
    acc[((q)>>1)*4+0][((q)&1)*2+1] = __builtin_amdgcn_mfma_f32_16x16x32_bf16(_a0, _b1, acc[((q)>>1)*4+0][((q)&1)*2+1], 0,0,0); \
    acc[((q)>>1)*4+1][((q)&1)*2+0] = __builtin_amdgcn_mfma_f32_16x16x32_bf16(_a1, _b0, acc[((q)>>1)*4+1][((q)&1)*2+0], 0,0,0); \
    acc[((q)>>1)*4+1][((q)&1)*2+1] = __builtin_amdgcn_mfma_f32_16x16x32_bf16(_a1, _b1, acc[((q)>>1)*4+1][((q)&1)*2+1], 0,0,0); \
    acc[((q)>>1)*4+2][((q)&1)*2+0] = __builtin_amdgcn_mfma_f32_16x16x32_bf16(_a2, _b0, acc[((q)>>1)*4+2][((q)&1)*2+0], 0,0,0); \
    acc[((q)>>1)*4+2][((q)&1)*2+1] = __builtin_amdgcn_mfma_f32_16x16x32_bf16(_a2, _b1, acc[((q)>>1)*4+2][((q)&1)*2+1], 0,0,0); \
    acc[((q)>>1)*4+3][((q)&1)*2+0] = __builtin_amdgcn_mfma_f32_16x16x32_bf16(_a3, _b0, acc[((q)>>1)*4+3][((q)&1)*2+0], 0,0,0); \
    acc[((q)>>1)*4+3][((q)&1)*2+1] = __builtin_amdgcn_mfma_f32_16x16x32_bf16(_a3, _b1, acc[((q)>>1)*4+3][((q)&1)*2+1], 0,0,0); \
    __builtin_amdgcn_s_setprio(0); \
    asm volatile("" ::: "memory"); \
    __builtin_amdgcn_s_barrier(); \
    asm volatile("" ::: "memory"); \
  } while (0)

template<int OUT>
__global__ __launch_bounds__(512, 2) void k_gemm8(
    const __bf16* __restrict__ A, const __bf16* __restrict__ Wt,
    void* __restrict__ Cv, int M, int N, int K, int lda, int mtiles,
    const int* __restrict__ idx, const float* __restrict__ gateb,
    const float* __restrict__ bhd, const float* __restrict__ bsc,
    const float* __restrict__ ub)
{
  __shared__ __attribute__((aligned(16))) unsigned char smem[98304];
  const int tid = threadIdx.x;
  const int nwg = gridDim.x;
  const int wg  = (blockIdx.x & 7) * (nwg >> 3) + (blockIdx.x >> 3);
  const int bm = wg % mtiles, bnn = wg / mtiles;
  const int m0 = bm << 8, n0 = bnn << 8;
  const int l = tid & 63, wid = tid >> 6;
  const int wr = wid >> 2, wc = wid & 3;
  const int fr = l & 15, g = l >> 4;

  f4 acc[8][4] = {};

  const int w16  = wid * 16;
  const int rsub = l >> 2;
  const int sseg = (l & 3) ^ ((l >= 32) ? 2 : 0);

  const int nk = K >> 5;
  const int ni = nk >> 1;

  STG8(0, 0, 0); STG8(0, 1, 0); STG8(0, 2, 0); STG8(0, 3, 0);
  STG8(1, 0, 1); STG8(1, 1, 1); STG8(1, 2, 1); STG8(1, 3, 1);
  asm volatile("s_waitcnt vmcnt(4)" ::: "memory");
  asm volatile("" ::: "memory");
  __builtin_amdgcn_s_barrier();
  asm volatile("" ::: "memory");

  int b0 = 0;
  for (int i = 0; i < ni; ++i) {
    const int b1 = (b0 == 2) ? 0 : b0 + 1;
    const int b2 = (b1 == 2) ? 0 : b1 + 1;
    const bool nlast = (i + 1 < ni);
    const int t2 = 2*i + 2, t3 = 2*i + 3;
    PH8(b0, 0, nlast, t2, 0, b2, -1);
    PH8(b0, 1, nlast, t2, 1, b2, -1);
    PH8(b0, 2, nlast, t2, 2, b2, -1);
    PH8(b0, 3, nlast, t2, 3, b2, nlast ? 4 : 0);
    PH8(b1, 0, nlast, t3, 0, b0, -1);
    PH8(b1, 1, nlast, t3, 1, b0, -1);
    PH8(b1, 2, nlast, t3, 2, b0, -1);
    PH8(b1, 3, nlast, t3, 3, b0, nlast ? 4 : -1);
    b0 = b2;
  }

  if constexpr (OUT == 1) {
    __bf16* C = (__bf16*)Cv;
#pragma unroll
    for (int ii = 0; ii < 8; ++ii) {
      int gm = m0 + wr*128 + ii*16 + g*4;
#pragma unroll
      for (int j = 0; j < 4; ++j) {
        int gn = n0 + wc*64 + j*16 + fr;
        if (gn < N) {
#pragma unroll
          for (int r = 0; r < 4; ++r)
            C[(size_t)(gm + r) * N + gn] = (__bf16)acc[ii][j][r];
        }
      }
    }
  } else {
    float* EP = (float*)smem;
    __syncthreads();
#pragma unroll
    for (int pass = 0; pass < 4; ++pass) {
      if (wr == (pass >> 1)) {
#pragma unroll
        for (int a = 0; a < 4; ++a) {
          int ii = (pass & 1)*4 + a;
#pragma unroll
          for (int j = 0; j < 4; ++j)
#pragma unroll
            for (int r = 0; r < 4; ++r)
              EP[(a*16 + g*4 + r)*256 + wc*64 + j*16 + fr] = acc[ii][j][r];
        }
      }
      __syncthreads();
#pragma unroll
      for (int it = 0; it < 8; ++it) {
        int row = it*8 + (tid >> 6);
        int c0  = (tid & 63) << 2;
        int grow = m0 + pass*64 + row;
        int gn = n0 + c0;
        float gt = gateb[grow];
        int tk = idx[grow];
        float4 a4 = *(float4*)&EP[row*256 + c0];
        float4 b4 = *(const float4*)&bhd[(size_t)tk * V_ + gn];
        float4 u4 = *(const float4*)&ub[gn];
        float4 s4 = *(const float4*)&bsc[gn];
        float4 o;
        o.x = SOFTCAPF * tanhf((a4.x + u4.x + gt*b4.x*s4.x) / SOFTCAPF);
        o.y = SOFTCAPF * tanhf((a4.y + u4.y + gt*b4.y*s4.y) / SOFTCAPF);
        o.z = SOFTCAPF * tanhf((a4.z + u4.z + gt*b4.z*s4.z) / SOFTCAPF);
        o.w = SOFTCAPF * tanhf((a4.w + u4.w + gt*b4.w*s4.w) / SOFTCAPF);
        *(float4*)&((float*)Cv)[(size_t)grow * N + gn] = o;
      }
      __syncthreads();
    }
  }
}
#undef PH8
#undef LDA8
#undef LDB8
#undef STG8

// ---------------- weight f32 -> bf16 convert ----------------
__global__ void k_cvt(const float* __restrict__ s, __bf16* __restrict__ d,
                      int perL, int K, int Kpad, long dstL, long dstOff, long nd4)
{
  long i = (long)blockIdx.x * 256 + threadIdx.x;
  if (i >= nd4) return;
  const int kp4 = Kpad >> 2;
  long row = i / kp4;
  int  c   = (int)(i % kp4) << 2;
  long layer = row / perL, r = row % perL;
  bf4 o;
  if (c < K) {
    float4 v = *(const float4*)(s + (layer*perL + r) * (long)K + c);
    o[0] = (__bf16)v.x; o[1] = (__bf16)v.y; o[2] = (__bf16)v.z; o[3] = (__bf16)v.w;
  } else { o[0] = o[1] = o[2] = o[3] = (__bf16)0.f; }
  *(bf4*)(d + layer*dstL + dstOff + (long)r*Kpad + c) = o;
}

// ---------------- embedding + rmsnorm ----------------
__global__ void k_embed(const int* __restrict__ idx, const float* __restrict__ emb,
                        const float* __restrict__ wn, float* __restrict__ x, float* __restrict__ x0)
{
  const int r = blockIdx.x, t = threadIdx.x;
  const float4 v = ((const float4*)(emb + (size_t)idx[r] * D_))[t];
  float ss = blocksum256(v.x*v.x + v.y*v.y + v.z*v.z + v.w*v.w);
  float rs = rsqrtf(ss / (float)D_ + EPSF);
  const float4 w = ((const float4*)wn)[t];
  float4 o = make_float4(v.x*rs*w.x, v.y*rs*w.y, v.z*rs*w.z, v.w*rs*w.w);
  ((float4*)(x  + (size_t)r * D_))[t] = o;
  ((float4*)(x0 + (size_t)r * D_))[t] = o;
}

// ---------------- block start: [x += msc*(t1a+t1b)] [skip store] [skip add] mix + norm ----------------
__global__ void k_blockstart(
    float* __restrict__ x, const float* __restrict__ x0,
    const __bf16* __restrict__ t1, const __bf16* __restrict__ t1p2,
    const float* __restrict__ msc,
    float* __restrict__ skstore, const float* __restrict__ skread, int same,
    const float* __restrict__ skw, const float* __restrict__ skg,
    const float* __restrict__ mix, const float* __restrict__ nw,
    __bf16* __restrict__ xn)
{
  const int r = blockIdx.x, t = threadIdx.x;
  const size_t i4 = (size_t)r * 256 + t;
  float4 xv = ((float4*)x)[i4];
  if (t1) {
    float4 tv = ld4b(t1, i4);
    float4 t2 = ld4b(t1p2, i4);
    float4 s  = ((const float4*)msc)[t];
    xv.x += s.x*(tv.x + t2.x); xv.y += s.y*(tv.y + t2.y);
    xv.z += s.z*(tv.z + t2.z); xv.w += s.w*(tv.w + t2.w);
  }
  if (skstore) ((float4*)skstore)[i4] = xv;
  if (skw) {
    float4 sv;
    if (same) sv = xv;
    else      sv = ((const float4*)skread)[i4];
    float4 w = ((const float4*)skw)[t];
    float4 g = ((const float4*)skg)[t];
    xv.x += w.x / (1.f + __expf(-g.x)) * sv.x;
    xv.y += w.y / (1.f + __expf(-g.y)) * sv.y;
    xv.z += w.z / (1.f + __expf(-g.z)) * sv.z;
    xv.w += w.w / (1.f + __expf(-g.w)) * sv.w;
  }
  float4 x0v = ((const float4*)x0)[i4];
  float4 m0  = ((const float4*)mix)[t];
  float4 m1  = ((const float4*)(mix + D_))[t];
  float4 nv;
  nv.x = m0.x*xv.x + m1.x*x0v.x; nv.y = m0.y*xv.y + m1.y*x0v.y;
  nv.z = m0.z*xv.z + m1.z*x0v.z; nv.w = m0.w*xv.w + m1.w*x0v.w;
  ((float4*)x)[i4] = nv;
  float ss = blocksum256(nv.x*nv.x + nv.y*nv.y + nv.z*nv.z + nv.w*nv.w);
  float rs = rsqrtf(ss / (float)D_ + EPSF);
  const float4 w = ((const float4*)nw)[t];
  bf4 o = { (__bf16)(nv.x*rs*w.x), (__bf16)(nv.y*rs*w.y),
            (__bf16)(nv.z*rs*w.z), (__bf16)(nv.w*rs*w.w) };
  ((bf4*)xn)[i4] = o;
}

// ---------------- x += sc*(t1a+t1b) ; xn = bf16(rmsnorm(x)*nw) ; optional gate ----------------
__global__ void k_addnorm(float* __restrict__ x, const __bf16* __restrict__ t1,
                          const __bf16* __restrict__ t1p2,
                          const float* __restrict__ sc, const float* __restrict__ nw,
                          __bf16* __restrict__ xn,
                          const float* __restrict__ bg, float* __restrict__ gateb)
{
  const int r = blockIdx.x, t = threadIdx.x;
  const size_t i4 = (size_t)r * 256 + t;
  float4 xv = ((float4*)x)[i4];
  float4 tv = ld4b(t1, i4);
  float4 t2 = ld4b(t1p2, i4);
  float4 s  = ((const float4*)sc)[t];
  xv.x += s.x*(tv.x + t2.x); xv.y += s.y*(tv.y + t2.y);
  xv.z += s.z*(tv.z + t2.z); xv.w += s.w*(tv.w + t2.w);
  ((float4*)x)[i4] = xv;
  float ss = blocksum256(xv.x*xv.x + xv.y*xv.y + xv.z*xv.z + xv.w*xv.w);
  float rs = rsqrtf(ss / (float)D_ + EPSF);
  const float4 w = ((const float4*)nw)[t];
  float ox = xv.x*rs*w.x, oy = xv.y*rs*w.y, oz = xv.z*rs*w.z, ow = xv.w*rs*w.w;
  bf4 o = { (__bf16)ox, (__bf16)oy, (__bf16)oz, (__bf16)ow };
  ((bf4*)xn)[i4] = o;
  if (bg) {
    float4 b4 = ((const float4*)bg)[t];
    float gd = ox*b4.x + oy*b4.y + oz*b4.z + ow*b4.w;
    __syncthreads();
    float gs = blocksum256(gd);
    if (t == 0) gateb[r] = 1.f / (1.f + __expf(-gs));
  }
}

// ---------------- rmsnorm D=1024, f32 in -> bf16 out ----------------
__global__ void k_rmsnormb(const float* __restrict__ in, const float* __restrict__ w,
                           __bf16* __restrict__ out)
{
  const int r = blockIdx.x, t = threadIdx.x;
  float4 v = ((const float4*)(in + (size_t)r * D_))[t];
  float ss = blocksum256(v.x*v.x + v.y*v.y + v.z*v.z + v.w*v.w);
  float rs = rsqrtf(ss / (float)D_ + EPSF);
  const float4 w4 = ((const float4*)w)[t];
  bf4 o = { (__bf16)(v.x*rs*w4.x), (__bf16)(v.y*rs*w4.y),
            (__bf16)(v.z*rs*w4.z), (__bf16)(v.w*rs*w4.w) };
  ((bf4*)(out + (size_t)r * D_))[t] = o;
}

// ---------------- dwconv helper over two bf16 partial planes ----------------
__device__ __forceinline__ float conv3b2(const __bf16* bA, const __bf16* bB,
                                         int tok, int s, int ld, int col,
                                         const float* w, int C, int c){
  const __bf16* pA = bA + (size_t)tok * ld + col;
  const __bf16* pB = bB + (size_t)tok * ld + col;
  float a  = (s >= 2) ? ((float)pA[-2*ld] + (float)pB[-2*ld]) : 0.f;
  float bb = (s >= 1) ? ((float)pA[-ld]   + (float)pB[-ld])   : 0.f;
  float cc = (float)pA[0] + (float)pB[0];
  return w[c]*a + w[C + c]*bb + w[2*C + c]*cc;
}

// ---------------- QKV prep: dwconv + head-rmsnorm + RoPE + q_gain -> bf16 (256 thr) ----------------
__global__ __launch_bounds__(256) void k_prep(
    const __bf16* __restrict__ qkv, const __bf16* __restrict__ qkv2,
    const float* __restrict__ qcw, const float* __restrict__ kcw, const float* __restrict__ vcw,
    const float* __restrict__ qgain,
    __bf16* __restrict__ q2, __bf16* __restrict__ k2, __bf16* __restrict__ v2)
{
  const int tok = blockIdx.x;
  const int s = tok & (S_ - 1);
  const int t = threadIdx.x, lane = t & 63, w = t >> 6;
  __shared__ float qsh[1024];

  const int j = lane & 31;
  float freq = __expf(-(float)j * (9.210340371976184f / 32.f));
  float sn, cs;
  __sincosf((float)s * freq, &sn, &cs);

#pragma unroll
  for (int k = 0; k < 4; ++k) {
    int c = t + k*256;
    float qc = conv3b2(qkv, qkv2, tok, s, 1536, c, qcw, D_, c);
    float ssq = wsum(qc * qc);
    float qn = qc * rsqrtf(ssq / 64.f + EPSF);
    float pr = __shfl_xor(qn, 32, 64);
    qsh[c] = qn * cs + ((lane < 32) ? pr * sn : -pr * sn);
  }
  __syncthreads();
  float qg[16];
#pragma unroll
  for (int g = 0; g < 16; ++g) qg[g] = qsh[g*64 + lane];
#pragma unroll
  for (int k = 0; k < 4; ++k) {
    int h = (k << 2) + w;
    float acc = 0.f;
#pragma unroll
    for (int g = 0; g < 16; ++g) acc += qgain[h*16 + g] * qg[g];
    q2[(size_t)tok * D_ + h*64 + lane] = (__bf16)acc;
  }

  {
    float kc = conv3b2(qkv, qkv2, tok, s, 1536, 1024 + t, kcw, KV_, t);
    float ssk = wsum(kc * kc);
    float kn = kc * rsqrtf(ssk / 64.f + EPSF);
    float pk = __shfl_xor(kn, 32, 64);
    k2[(size_t)tok * KV_ + t] = (__bf16)(kn * cs + ((lane < 32) ? pk * sn : -pk * sn));
  }
  v2[(size_t)tok * KV_ + t] = (__bf16)conv3b2(qkv, qkv2, tok, s, 1536, 1280 + t, vcw, KV_, t);
}

// ---------------- MFMA flash attention (bf16 compute, f32 accumulate) ----------------
// qb-flip load balance: co-resident block pair (id, id+256) differs only in b.
#define LDK 72
__global__ __launch_bounds__(256) void k_attn(
    const __bf16* __restrict__ q2, const __bf16* __restrict__ k2,
    const __bf16* __restrict__ v2, float* __restrict__ y)
{
  __shared__ __attribute__((aligned(16))) __bf16 Ks[64*LDK];
  __shared__ __attribute__((aligned(16))) __bf16 Vt[64*LDK];
  __shared__ __attribute__((aligned(16))) __bf16 Ps[4][16*LDK];

  const int id = blockIdx.x;
  const int h  = (id >> 4) & 15;
  const int b  = id >> 8;
  const int qb = b ? (15 - (id & 15)) : (id & 15);
  const int tid = threadIdx.x, l = tid & 63, wq = tid >> 6;
  const int g = l >> 4, fr = l & 15;
  const int kvh = h >> 2;
  const int qrow = qb*64 + wq*16 + fr;

  bf8 qf[2];
#pragma unroll
  for (int ks = 0; ks < 2; ++ks)
    qf[ks] = *(const bf8*)&q2[(size_t)(b*S_ + qrow)*D_ + h*64 + g*8 + ks*32];

  float m = -1e30f, lsum = 0.f;
  f4 acc[4] = {};

  const int nch = qb + 1;
  for (int ch = 0; ch < nch; ++ch) {
    const int t0 = ch << 6;
    __syncthreads();
#pragma unroll
    for (int it = 0; it < 2; ++it) {
      int i = tid + it*256;
      int row = i >> 3, seg = (i & 7) << 3;
      *(bf8*)&Ks[row*LDK + seg] =
        *(const bf8*)&k2[(size_t)(b*S_ + t0 + row)*KV_ + kvh*64 + seg];
    }
    {
      int key4 = (tid & 15) << 2, hd4 = (tid >> 4) << 2;
      bf4 vv[4];
#pragma unroll
      for (int kk = 0; kk < 4; ++kk)
        vv[kk] = *(const bf4*)&v2[(size_t)(b*S_ + t0 + key4 + kk)*KV_ + kvh*64 + hd4];
#pragma unroll
      for (int hh = 0; hh < 4; ++hh) {
        bf4 w = { vv[0][hh], vv[1][hh], vv[2][hh], vv[3][hh] };
        *(bf4*)&Vt[(hd4 + hh)*LDK + key4] = w;
      }
    }
    __syncthreads();

    f4 sc[4] = {};
#pragma unroll
    for (int ks = 0; ks < 2; ++ks)
#pragma unroll
      for (int t = 0; t < 4; ++t) {
        bf8 kf = *(const bf8*)&Ks[(t*16 + fr)*LDK + g*8 + ks*32];
        sc[t] = __builtin_amdgcn_mfma_f32_16x16x32_bf16(kf, qf[ks], sc[t], 0, 0, 0);
      }

    const bool lastch = (ch == qb);
    float s[4][4];
    float pmax = -1e30f;
#pragma unroll
    for (int t = 0; t < 4; ++t)
#pragma unroll
      for (int r = 0; r < 4; ++r) {
        float v = sc[t][r] * 0.125f;
        if (lastch && (t0 + t*16 + g*4 + r > qrow)) v = -1e30f;
        s[t][r] = v;
        pmax = fmaxf(pmax, v);
      }
    pmax = fmaxf(pmax, __shfl_xor(pmax, 16, 64));
    pmax = fmaxf(pmax, __shfl_xor(pmax, 32, 64));
    float mnew = fmaxf(m, pmax);
    float alpha = __expf(m - mnew);
    float rs = 0.f;
#pragma unroll
    for (int t = 0; t < 4; ++t)
#pragma unroll
      for (int r = 0; r < 4; ++r) { float p = __expf(s[t][r] - mnew); s[t][r] = p; rs += p; }
    rs += __shfl_xor(rs, 16, 64);
    rs += __shfl_xor(rs, 32, 64);
    lsum = lsum * alpha + rs;
    m = mnew;
#pragma unroll
    for (int t = 0; t < 4; ++t) acc[t] = acc[t] * alpha;

#pragma unroll
    for (int t = 0; t < 4; ++t) {
      bf4 pw = { (__bf16)s[t][0], (__bf16)s[t][1], (__bf16)s[t][2], (__bf16)s[t][3] };
      *(bf4*)&Ps[wq][fr*LDK + t*16 + g*4] = pw;
    }

#pragma unroll
    for (int ks = 0; ks < 2; ++ks) {
      bf8 pf = *(const bf8*)&Ps[wq][fr*LDK + g*8 + ks*32];
#pragma unroll
      for (int t = 0; t < 4; ++t) {
        bf8 vf = *(const bf8*)&Vt[(t*16 + fr)*LDK + g*8 + ks*32];
        acc[t] = __builtin_amdgcn_mfma_f32_16x16x32_bf16(vf, pf, acc[t], 0, 0, 0);
      }
    }
  }

  float inv = 1.f / lsum;
#pragma unroll
  for (int t = 0; t < 4; ++t)
#pragma unroll
    for (int r = 0; r < 4; ++r)
      y[(size_t)(b*S_ + qrow)*D_ + h*64 + t*16 + g*4 + r] = acc[t][r] * inv;
}

// ---------------- fused silu*mul + dwconv + rmsnorm -> bf16 (reads bf16 hb) ----------------
__device__ __forceinline__ float hprodb(const __bf16* row, int c){
  float a = (float)row[c], b = (float)row[HID_ + c];
  return a * b / (1.f + __expf(-b));
}
__global__ __launch_bounds__(256) void k_hfuse(
    const __bf16* __restrict__ hb, const float* __restrict__ cw,
    const float* __restrict__ nw, __bf16* __restrict__ out)
{
  const int tok = blockIdx.x, t = threadIdx.x;
  const int s = tok & (S_ - 1);
  const __bf16* row0 = hb + (size_t)tok * 5472;
  float v[11]; float ss = 0.f;
#pragma unroll
  for (int ii = 0; ii < 11; ++ii) {
    int c = t + ii*256;
    float cv = 0.f;
    if (c < HID_) {
      float p0 = hprodb(row0, c);
      float p1 = (s >= 1) ? hprodb(row0 - 5472, c) : 0.f;
      float p2 = (s >= 2) ? hprodb(row0 - 2*5472, c) : 0.f;
      cv = cw[c]*p2 + cw[HID_ + c]*p1 + cw[2*HID_ + c]*p0;
    }
    v[ii] = cv; ss += cv*cv;
  }
  ss = blocksum256(ss);
  float rs = rsqrtf(ss / (float)HID_ + EPSF);
#pragma unroll
  for (int ii = 0; ii < 11; ++ii) {
    int c = t + ii*256;
    if (c < HIDP)
      out[(size_t)tok * HIDP + c] = (c < HID_) ? (__bf16)(v[ii]*rs*nw[c]) : (__bf16)0.f;
  }
}

// ---------------- host ----------------
template<int BM, int BN, int OUT, int SK>
static inline void gemm(const __bf16* A, const __bf16* W, void* C, int M, int N, int K,
                        int lda, hipStream_t s)
{
  int mt = M / BM, nt = (N + BN - 1) / BN;
  k_gemm<BM, BN, OUT, SK><<<dim3(mt * nt * SK), dim3(256), 0, s>>>(A, W, C, M, N, K, lda, mt);
}

template<int OUT>
static inline void gemm8(const __bf16* A, const __bf16* W, void* C, int M, int N, int K,
                         int lda, hipStream_t s,
                         const int* idx = nullptr, const float* gateb = nullptr,
                         const float* bhd = nullptr, const float* bsc = nullptr,
                         const float* ub = nullptr)
{
  int mt = M >> 8, nt = (N + 255) >> 8;
  k_gemm8<OUT><<<dim3(mt * nt), dim3(512), 0, s>>>(A, W, C, M, N, K, lda, mt,
                                                   idx, gateb, bhd, bsc, ub);
}

extern "C" void kernel_launch(void* const* d_in, const int* in_sizes, int n_in,
                              void* d_out, int out_size, void* d_ws, size_t ws_size,
                              hipStream_t stream)
{
  const int*   idx    = (const int*)d_in[0];
  const float* temb   = (const float*)d_in[1];
  const float* enw    = (const float*)d_in[2];
  const float* rmix   = (const float*)d_in[3];
  const float* anw    = (const float*)d_in[4];
  const float* mnw    = (const float*)d_in[5];
  const float* ascale = (const float*)d_in[6];
  const float* mscale = (const float*)d_in[7];
  const float* Wq     = (const float*)d_in[8];
  const float* Wk     = (const float*)d_in[9];
  const float* Wv     = (const float*)d_in[10];
  const float* qcw    = (const float*)d_in[11];
  const float* kcw    = (const float*)d_in[12];
  const float* vcw    = (const float*)d_in[13];
  const float* qgain  = (const float*)d_in[14];
  const float* panw   = (const float*)d_in[15];
  const float* Wo     = (const float*)d_in[16];
  const float* Wfc    = (const float*)d_in[17];
  const float* Wgate  = (const float*)d_in[18];
  const float* hcw    = (const float*)d_in[19];
  const float* hnw    = (const float*)d_in[20];
  const float* Wmp    = (const float*)d_in[21];
  const float* skw    = (const float*)d_in[22];
  const float* skg    = (const float*)d_in[23];
  const float* fnw    = (const float*)d_in[24];
  const float* lmw    = (const float*)d_in[25];
  const float* bh     = (const float*)d_in[26];
  const float* bsc    = (const float*)d_in[27];
  const float* bg     = (const float*)d_in[28];
  const float* ub     = (const float*)d_in[29];

  float* p = (float*)d_ws;
  float* x    = p; p += (size_t)NT_ * D_;
  float* x0   = p; p += (size_t)NT_ * D_;
  float* y    = p; p += (size_t)NT_ * D_;
  float* skips= p; p += (size_t)4 * NT_ * D_;
  float* gateb= p; p += NT_;
  __bf16* qkvb= (__bf16*)p; p += (size_t)2 * NT_ * 1536 / 2;   // 2 split-K planes
  __bf16* hbb = (__bf16*)p; p += (size_t)NT_ * 5472 / 2;
  __bf16* t1b = (__bf16*)p; p += (size_t)2 * NT_ * D_ / 2;     // 2 split-K planes
  __bf16* xnb = (__bf16*)p; p += (size_t)NT_ * D_ / 2;
  __bf16* q2b = (__bf16*)p; p += (size_t)NT_ * D_ / 2;
  __bf16* k2b = (__bf16*)p; p += (size_t)NT_ * KV_ / 2;
  __bf16* v2b = (__bf16*)p; p += (size_t)NT_ * KV_ / 2;
  __bf16* hnb = (__bf16*)p; p += (size_t)NT_ * HIDP / 2;
  __bf16* wqkv= (__bf16*)p; p += (size_t)L_ * 1536 * 1024 / 2;
  __bf16* wob = (__bf16*)p; p += (size_t)L_ * 1024 * 1024 / 2;
  __bf16* wfcg= (__bf16*)p; p += (size_t)L_ * 5472 * 1024 / 2;
  __bf16* wmpb= (__bf16*)p; p += (size_t)L_ * 1024 * HIDP / 2;
  __bf16* wlmb= (__bf16*)p; p += (size_t)V_ * 1024 / 2;
  float* logits = (float*)d_out;

  const __bf16* qkvb2 = qkvb + (size_t)NT_ * 1536;
  const __bf16* t1b2  = t1b + (size_t)NT_ * D_;

  // ---- weight conversions (every launch; deterministic) ----
  auto cvt = [&](const float* s, __bf16* d, int perL, int K, int Kpad,
                 long dstL, long dstOff, int nl) {
    long nd4 = (long)nl * perL * (Kpad >> 2);
    int grid = (int)((nd4 + 255) / 256);
    k_cvt<<<grid, 256, 0, stream>>>(s, d, perL, K, Kpad, dstL, dstOff, nd4);
  };
  cvt(Wq,    wqkv, 1024, 1024, 1024, 1536L*1024, 0,          L_);
  cvt(Wk,    wqkv,  256, 1024, 1024, 1536L*1024, 1024L*1024, L_);
  cvt(Wv,    wqkv,  256, 1024, 1024, 1536L*1024, 1280L*1024, L_);
  cvt(Wo,    wob,  1024, 1024, 1024, 1024L*1024, 0,          L_);
  cvt(Wfc,   wfcg, 2736, 1024, 1024, 5472L*1024, 0,          L_);
  cvt(Wgate, wfcg, 2736, 1024, 1024, 5472L*1024, 2736L*1024, L_);
  cvt(Wmp,   wmpb, 1024, 2736, HIDP, 1024L*HIDP, 0,          L_);
  cvt(lmw,   wlmb, 8192, 1024, 1024, 8192L*1024, 0,          1);

  k_embed<<<NT_, 256, 0, stream>>>(idx, temb, enw, x, x0);

  for (int i = 0; i < L_; ++i) {
    const float* pmsc = (i > 0) ? mscale + (size_t)(i-1) * D_ : nullptr;
    float* skst = (i >= 1 && i <= 4) ? skips + (size_t)(i-1) * NT_ * D_ : nullptr;
    const float* skrd = (i >= 4) ? skips + (size_t)(7-i) * NT_ * D_ : nullptr;
    const float* swp = (i >= 4) ? skw + (size_t)(i-4) * D_ : nullptr;
    const float* sgp = (i >= 4) ? skg + (size_t)(i-4) * D_ : nullptr;
    k_blockstart<<<NT_, 256, 0, stream>>>(x, x0, (i > 0) ? t1b : nullptr, t1b2, pmsc,
                                          skst, skrd, (i == 4) ? 1 : 0, swp, sgp,
                                          rmix + (size_t)i * 2 * D_,
                                          anw + (size_t)i * D_, xnb);
    gemm<64, 128, 1, 2>(xnb, wqkv + (size_t)i * 1536 * 1024, qkvb, NT_, 1536, 1024, 1024, stream);
    k_prep<<<NT_, 256, 0, stream>>>(qkvb, qkvb2,
                                    qcw + (size_t)i * 3 * D_, kcw + (size_t)i * 3 * KV_,
                                    vcw + (size_t)i * 3 * KV_, qgain + (size_t)i * H_ * H_,
                                    q2b, k2b, v2b);
    k_attn<<<B_ * H_ * (S_/64), 256, 0, stream>>>(q2b, k2b, v2b, y);
    k_rmsnormb<<<NT_, 256, 0, stream>>>(y, panw + (size_t)i * D_, xnb);
    gemm<64, 64, 1, 2>(xnb, wob + (size_t)i * 1024 * 1024, t1b, NT_, 1024, 1024, 1024, stream);
    k_addnorm<<<NT_, 256, 0, stream>>>(x, t1b, t1b2, ascale + (size_t)i * D_,
                                       mnw + (size_t)i * D_, xnb, nullptr, nullptr);
    gemm8<1>(xnb, wfcg + (size_t)i * 5472 * 1024, hbb, NT_, 5472, 1024, 1024, stream);
    k_hfuse<<<NT_, 256, 0, stream>>>(hbb, hcw + (size_t)i * 3 * HID_,
                                     hnw + (size_t)i * HID_, hnb);
    gemm<64, 64, 1, 2>(hnb, wmpb + (size_t)i * 1024 * HIDP, t1b, NT_, 1024, HIDP, HIDP, stream);
  }

  // final: mlp7 residual + final norm + bigram gate
  k_addnorm<<<NT_, 256, 0, stream>>>(x, t1b, t1b2, mscale + (size_t)7 * D_, fnw, xnb, bg, gateb);
  gemm8<2>(xnb, wlmb, logits, NT_, V_, 1024, 1024, stream, idx, gateb, bh, bsc, ub);
}